// Round 1
// baseline (5043.646 us; speedup 1.0000x reference)
//
#include <hip/hip_runtime.h>
#include <hip/hip_bf16.h>
#include <math.h>

#define B 4
#define L 512
#define D 384
#define NL 8
#define DS 16
#define DC 4
#define DI 768
#define DTR 24
#define G (DTR + 2*DS)   // 56
#define ED 256
#define M (B*L)          // 2048

// ---------------- embed: x = emb[ids] + pos ----------------
__global__ __launch_bounds__(256) void embed_kernel(const int* __restrict__ ids,
    const float* __restrict__ emb, const float* __restrict__ pos, float* __restrict__ x) {
  int idx = blockIdx.x * 256 + threadIdx.x;
  if (idx >= M * D) return;
  int m = idx / D, d = idx - m * D;
  int l = m & (L - 1);
  x[idx] = emb[(size_t)ids[m] * D + d] + pos[l * D + d];
}

// ---------------- layernorm: one wave per row of D=384 ----------------
__global__ __launch_bounds__(64) void layernorm_kernel(const float* __restrict__ x,
    const float* __restrict__ g, const float* __restrict__ b, float* __restrict__ o) {
  int row = blockIdx.x;
  int t = threadIdx.x;
  const float* xr = x + (size_t)row * D;
  float v[6];
  float s = 0.f;
#pragma unroll
  for (int i = 0; i < 6; i++) { v[i] = xr[t + i * 64]; s += v[i]; }
#pragma unroll
  for (int o_ = 32; o_ > 0; o_ >>= 1) s += __shfl_xor(s, o_);
  float mean = s * (1.0f / D);
  float vs = 0.f;
#pragma unroll
  for (int i = 0; i < 6; i++) { float dd = v[i] - mean; vs += dd * dd; }
#pragma unroll
  for (int o_ = 32; o_ > 0; o_ >>= 1) vs += __shfl_xor(vs, o_);
  float inv = 1.0f / sqrtf(vs * (1.0f / D) + 1e-5f);
  float* orow = o + (size_t)row * D;
#pragma unroll
  for (int i = 0; i < 6; i++) {
    int d = t + i * 64;
    orow[d] = (v[i] - mean) * inv * g[d] + b[d];
  }
}

// ---------------- GEMM: C[M,N] = A[M,K] @ W[N,K]^T (+C if ADD) ----------------
template <int ADD>
__global__ __launch_bounds__(256) void gemm_kernel(const float* __restrict__ A,
    const float* __restrict__ W, float* __restrict__ C, int Mm, int Nn, int Kk) {
  __shared__ float As[64][20];
  __shared__ float Ws[64][20];
  int t = threadIdx.x;
  int m0 = blockIdx.x * 64;
  int n0 = blockIdx.y * 64;
  int tm = t >> 4, tn = t & 15;
  float acc[4][4] = {};
  int r = t >> 2;          // 0..63
  int kv = (t & 3) * 4;    // 0,4,8,12

  for (int k0 = 0; k0 < Kk; k0 += 16) {
    float4 av = {0, 0, 0, 0};
    {
      int gm = m0 + r, gk = k0 + kv;
      if (gm < Mm) {
        if (gk + 3 < Kk) av = *(const float4*)(A + (size_t)gm * Kk + gk);
        else {
          float* p = (float*)&av;
          for (int j = 0; j < 4; j++) p[j] = (gk + j < Kk) ? A[(size_t)gm * Kk + gk + j] : 0.f;
        }
      }
    }
    float4 wv = {0, 0, 0, 0};
    {
      int gn = n0 + r, gk = k0 + kv;
      if (gn < Nn) {
        if (gk + 3 < Kk) wv = *(const float4*)(W + (size_t)gn * Kk + gk);
        else {
          float* p = (float*)&wv;
          for (int j = 0; j < 4; j++) p[j] = (gk + j < Kk) ? W[(size_t)gn * Kk + gk + j] : 0.f;
        }
      }
    }
    __syncthreads();
    *(float4*)&As[r][kv] = av;
    *(float4*)&Ws[r][kv] = wv;
    __syncthreads();
#pragma unroll
    for (int kk4 = 0; kk4 < 4; kk4++) {
      float4 a4[4], b4[4];
#pragma unroll
      for (int i = 0; i < 4; i++) a4[i] = *(const float4*)&As[tm * 4 + i][kk4 * 4];
#pragma unroll
      for (int j = 0; j < 4; j++) b4[j] = *(const float4*)&Ws[tn * 4 + j][kk4 * 4];
#pragma unroll
      for (int i = 0; i < 4; i++)
#pragma unroll
        for (int j = 0; j < 4; j++)
          acc[i][j] += a4[i].x * b4[j].x + a4[i].y * b4[j].y + a4[i].z * b4[j].z + a4[i].w * b4[j].w;
    }
  }
#pragma unroll
  for (int i = 0; i < 4; i++) {
    int gm = m0 + tm * 4 + i;
    if (gm >= Mm) continue;
#pragma unroll
    for (int j = 0; j < 4; j++) {
      int gn = n0 + tn * 4 + j;
      if (gn >= Nn) continue;
      float vv = acc[i][j];
      if (ADD) vv += C[(size_t)gm * Nn + gn];
      C[(size_t)gm * Nn + gn] = vv;
    }
  }
}

// ---------------- causal conv (DC=4) + silu ----------------
__global__ __launch_bounds__(256) void conv_silu_kernel(const float* __restrict__ xz,
    const float* __restrict__ cw, const float* __restrict__ cb, float* __restrict__ xc) {
  int idx = blockIdx.x * 256 + threadIdx.x;
  if (idx >= M * DI) return;
  int m = idx / DI, e = idx - m * DI;
  int l = m & (L - 1);
  float acc = cb[e];
#pragma unroll
  for (int k = 0; k < DC; k++) {
    int ll = l - (DC - 1) + k;
    if (ll >= 0) acc += xz[(size_t)(m - (DC - 1) + k) * (2 * DI) + e] * cw[e * DC + k];
  }
  xc[idx] = acc / (1.f + expf(-acc));  // silu
}

// ---------------- dt = softplus(dt_r @ dtw^T + dtb), K=24 ----------------
__global__ __launch_bounds__(256) void dt_kernel(const float* __restrict__ dbc,
    const float* __restrict__ dtw, const float* __restrict__ dtb, float* __restrict__ dt) {
  int tok = blockIdx.x;
  __shared__ float rr[DTR];
  int t = threadIdx.x;
  if (t < DTR) rr[t] = dbc[(size_t)tok * G + t];
  __syncthreads();
  for (int d = t; d < DI; d += 256) {
    float acc = dtb[d];
#pragma unroll
    for (int k = 0; k < DTR; k++) acc += rr[k] * dtw[d * DTR + k];
    dt[(size_t)tok * DI + d] = (acc > 20.f) ? acc : log1pf(expf(acc));
  }
}

// ---------------- selective scan: 16 lanes per (b,d) channel ----------------
__global__ __launch_bounds__(256) void scan_kernel(const float* __restrict__ dbc,
    const float* __restrict__ dt, const float* __restrict__ xconv, const float* __restrict__ xz,
    const float* __restrict__ A_log, const float* __restrict__ Dp, float* __restrict__ y) {
  int b = blockIdx.x;   // 0..3
  int dg = blockIdx.y;  // 0..47
  int t = threadIdx.x;
  int ld = t >> 4;      // 0..15
  int n = t & 15;       // state index
  int d = dg * 16 + ld;
  float Av = -expf(A_log[d * DS + n]);
  float Dv = Dp[d];
  float h = 0.f;
  size_t base = (size_t)b * L;
  for (int l = 0; l < L; l++) {
    size_t tok = base + l;
    float dtv = dt[tok * DI + d];
    float xcv = xconv[tok * DI + d];
    float Bn = dbc[tok * G + DTR + n];
    float Cn = dbc[tok * G + DTR + DS + n];
    float dA = expf(dtv * Av);
    h = dA * h + dtv * Bn * xcv;
    float p = h * Cn;
#pragma unroll
    for (int o_ = 1; o_ < 16; o_ <<= 1) p += __shfl_xor(p, o_);
    if (n == 0) {
      float zv = xz[tok * (2 * DI) + DI + d];
      float yv = (p + Dv * xcv) * (zv / (1.f + expf(-zv)));
      y[tok * DI + d] = yv;
    }
  }
}

// ---------------- masked mean pool ----------------
__global__ __launch_bounds__(128) void pool_kernel(const float* __restrict__ xf,
    const int* __restrict__ ids, float* __restrict__ pooled) {
  int b = blockIdx.x;
  int t = threadIdx.x;  // 0..127, covers 384 in 3 strides
  float cnt = 0.f;
  float sums[3] = {};
  for (int l = 0; l < L; l++) {
    int tok = b * L + l;
    float msk = (ids[tok] != 0) ? 1.f : 0.f;
    cnt += msk;
#pragma unroll
    for (int i = 0; i < 3; i++) sums[i] += msk * xf[(size_t)tok * D + t + i * 128];
  }
  float denom = fmaxf(cnt, 1.f);
#pragma unroll
  for (int i = 0; i < 3; i++) pooled[b * D + t + i * 128] = sums[i] / denom;
}

// ---------------- final proj + L2 normalize ----------------
__global__ __launch_bounds__(256) void proj_norm_kernel(const float* __restrict__ pooled,
    const float* __restrict__ pw, const float* __restrict__ pb, float* __restrict__ out) {
  int b = blockIdx.x;
  int t = threadIdx.x;  // one output per thread (ED=256)
  __shared__ float pr[D];
  __shared__ float red[256];
  for (int i = t; i < D; i += 256) pr[i] = pooled[b * D + i];
  __syncthreads();
  float acc = pb[t];
  for (int k = 0; k < D; k++) acc += pr[k] * pw[t * D + k];
  red[t] = acc * acc;
  __syncthreads();
  for (int s = 128; s > 0; s >>= 1) {
    if (t < s) red[t] += red[t + s];
    __syncthreads();
  }
  float nrm = sqrtf(red[0]);
  float scale = 1.f / fmaxf(nrm, 1e-12f);
  out[b * ED + t] = acc * scale;
}

extern "C" void kernel_launch(void* const* d_in, const int* in_sizes, int n_in,
                              void* d_out, int out_size, void* d_ws, size_t ws_size,
                              hipStream_t stream) {
  const int*   ids  = (const int*)d_in[0];
  const float* emb  = (const float*)d_in[1];
  const float* pos  = (const float*)d_in[2];
  const float* ln_g = (const float*)d_in[3];
  const float* ln_b = (const float*)d_in[4];
  const float* inw  = (const float*)d_in[5];
  const float* cw   = (const float*)d_in[6];
  const float* cb   = (const float*)d_in[7];
  const float* xw   = (const float*)d_in[8];
  const float* dtw  = (const float*)d_in[9];
  const float* dtb  = (const float*)d_in[10];
  const float* Alog = (const float*)d_in[11];
  const float* Dp   = (const float*)d_in[12];
  const float* ow   = (const float*)d_in[13];
  const float* flng = (const float*)d_in[14];
  const float* flnb = (const float*)d_in[15];
  const float* pw   = (const float*)d_in[16];
  const float* pb   = (const float*)d_in[17];
  float* out = (float*)d_out;

  float* ws    = (float*)d_ws;
  float* x     = ws;                        // M*D
  float* xln   = x + (size_t)M * D;         // M*D
  float* xz    = xln + (size_t)M * D;       // M*2DI
  float* xconv = xz + (size_t)M * 2 * DI;   // M*DI
  float* dbc   = xconv + (size_t)M * DI;    // M*G
  float* dtb_  = dbc + (size_t)M * G;       // M*DI
  float* ybuf  = dtb_ + (size_t)M * DI;     // M*DI
  float* pooled = ybuf + (size_t)M * DI;    // B*D

  embed_kernel<<<(M * D + 255) / 256, 256, 0, stream>>>(ids, emb, pos, x);

  for (int i = 0; i < NL; i++) {
    layernorm_kernel<<<M, 64, 0, stream>>>(x, ln_g + i * D, ln_b + i * D, xln);

    dim3 g1(M / 64, (2 * DI) / 64);
    gemm_kernel<0><<<g1, 256, 0, stream>>>(xln, inw + (size_t)i * 2 * DI * D, xz, M, 2 * DI, D);

    conv_silu_kernel<<<(M * DI + 255) / 256, 256, 0, stream>>>(
        xz, cw + (size_t)i * DI * DC, cb + (size_t)i * DI, xconv);

    dim3 g2(M / 64, (G + 63) / 64);
    gemm_kernel<0><<<g2, 256, 0, stream>>>(xconv, xw + (size_t)i * G * DI, dbc, M, G, DI);

    dt_kernel<<<M, 256, 0, stream>>>(dbc, dtw + (size_t)i * DI * DTR, dtb + (size_t)i * DI, dtb_);

    dim3 gs(B, DI / 16);
    scan_kernel<<<gs, 256, 0, stream>>>(dbc, dtb_, xconv, xz,
        Alog + (size_t)i * DI * DS, Dp + (size_t)i * DI, ybuf);

    dim3 g3(M / 64, D / 64);
    gemm_kernel<1><<<g3, 256, 0, stream>>>(ybuf, ow + (size_t)i * D * DI, x, M, D, DI);
  }

  layernorm_kernel<<<M, 64, 0, stream>>>(x, flng, flnb, xln);
  pool_kernel<<<B, 128, 0, stream>>>(xln, ids, pooled);
  proj_norm_kernel<<<B, ED, 0, stream>>>(pooled, pw, pb, out);
}

// Round 5
// 2440.327 us; speedup vs baseline: 2.0668x; 2.0668x over previous
//
#include <hip/hip_runtime.h>
#include <hip/hip_bf16.h>
#include <math.h>

#define B 4
#define L 512
#define D 384
#define NL 8
#define DS 16
#define DC 4
#define DI 768
#define DTR 24
#define G (DTR + 2*DS)   // 56
#define ED 256
#define M (B*L)          // 2048
#define NCH 8            // chunks along L
#define CHL (L/NCH)      // 64 tokens per chunk

// ---------------- embed: x = emb[ids] + pos ----------------
__global__ __launch_bounds__(256) void embed_kernel(const int* __restrict__ ids,
    const float* __restrict__ emb, const float* __restrict__ pos, float* __restrict__ x) {
  int idx = blockIdx.x * 256 + threadIdx.x;
  if (idx >= M * D) return;
  int m = idx / D, d = idx - m * D;
  int l = m & (L - 1);
  x[idx] = emb[(size_t)ids[m] * D + d] + pos[l * D + d];
}

// ---------------- layernorm: one wave per row of D=384 ----------------
__global__ __launch_bounds__(64) void layernorm_kernel(const float* __restrict__ x,
    const float* __restrict__ g, const float* __restrict__ b, float* __restrict__ o) {
  int row = blockIdx.x;
  int t = threadIdx.x;
  const float* xr = x + (size_t)row * D;
  float v[6];
  float s = 0.f;
#pragma unroll
  for (int i = 0; i < 6; i++) { v[i] = xr[t + i * 64]; s += v[i]; }
#pragma unroll
  for (int o_ = 32; o_ > 0; o_ >>= 1) s += __shfl_xor(s, o_);
  float mean = s * (1.0f / D);
  float vs = 0.f;
#pragma unroll
  for (int i = 0; i < 6; i++) { float dd = v[i] - mean; vs += dd * dd; }
#pragma unroll
  for (int o_ = 32; o_ > 0; o_ >>= 1) vs += __shfl_xor(vs, o_);
  float inv = 1.0f / sqrtf(vs * (1.0f / D) + 1e-5f);
  float* orow = o + (size_t)row * D;
#pragma unroll
  for (int i = 0; i < 6; i++) {
    int d = t + i * 64;
    orow[d] = (v[i] - mean) * inv * g[d] + b[d];
  }
}

// ---------------- GEMM: C[M,N] = A[M,K] @ W[N,K]^T (+C if ADD) ----------------
template <int ADD>
__global__ __launch_bounds__(256) void gemm_kernel(const float* __restrict__ A,
    const float* __restrict__ W, float* __restrict__ C, int Mm, int Nn, int Kk) {
  __shared__ float As[64][20];
  __shared__ float Ws[64][20];
  int t = threadIdx.x;
  int m0 = blockIdx.x * 64;
  int n0 = blockIdx.y * 64;
  int tm = t >> 4, tn = t & 15;
  float acc[4][4] = {};
  int r = t >> 2;          // 0..63
  int kv = (t & 3) * 4;    // 0,4,8,12

  for (int k0 = 0; k0 < Kk; k0 += 16) {
    float4 av = {0, 0, 0, 0};
    {
      int gm = m0 + r, gk = k0 + kv;
      if (gm < Mm) {
        if (gk + 3 < Kk) av = *(const float4*)(A + (size_t)gm * Kk + gk);
        else {
          float* p = (float*)&av;
          for (int j = 0; j < 4; j++) p[j] = (gk + j < Kk) ? A[(size_t)gm * Kk + gk + j] : 0.f;
        }
      }
    }
    float4 wv = {0, 0, 0, 0};
    {
      int gn = n0 + r, gk = k0 + kv;
      if (gn < Nn) {
        if (gk + 3 < Kk) wv = *(const float4*)(W + (size_t)gn * Kk + gk);
        else {
          float* p = (float*)&wv;
          for (int j = 0; j < 4; j++) p[j] = (gk + j < Kk) ? W[(size_t)gn * Kk + gk + j] : 0.f;
        }
      }
    }
    __syncthreads();
    *(float4*)&As[r][kv] = av;
    *(float4*)&Ws[r][kv] = wv;
    __syncthreads();
#pragma unroll
    for (int kk4 = 0; kk4 < 4; kk4++) {
      float4 a4[4], b4[4];
#pragma unroll
      for (int i = 0; i < 4; i++) a4[i] = *(const float4*)&As[tm * 4 + i][kk4 * 4];
#pragma unroll
      for (int j = 0; j < 4; j++) b4[j] = *(const float4*)&Ws[tn * 4 + j][kk4 * 4];
#pragma unroll
      for (int i = 0; i < 4; i++)
#pragma unroll
        for (int j = 0; j < 4; j++)
          acc[i][j] += a4[i].x * b4[j].x + a4[i].y * b4[j].y + a4[i].z * b4[j].z + a4[i].w * b4[j].w;
    }
  }
#pragma unroll
  for (int i = 0; i < 4; i++) {
    int gm = m0 + tm * 4 + i;
    if (gm >= Mm) continue;
#pragma unroll
    for (int j = 0; j < 4; j++) {
      int gn = n0 + tn * 4 + j;
      if (gn >= Nn) continue;
      float vv = acc[i][j];
      if (ADD) vv += C[(size_t)gm * Nn + gn];
      C[(size_t)gm * Nn + gn] = vv;
    }
  }
}

// ---------------- causal conv (DC=4) + silu ----------------
__global__ __launch_bounds__(256) void conv_silu_kernel(const float* __restrict__ xz,
    const float* __restrict__ cw, const float* __restrict__ cb, float* __restrict__ xc) {
  int idx = blockIdx.x * 256 + threadIdx.x;
  if (idx >= M * DI) return;
  int m = idx / DI, e = idx - m * DI;
  int l = m & (L - 1);
  float acc = cb[e];
#pragma unroll
  for (int k = 0; k < DC; k++) {
    int ll = l - (DC - 1) + k;
    if (ll >= 0) acc += xz[(size_t)(m - (DC - 1) + k) * (2 * DI) + e] * cw[e * DC + k];
  }
  xc[idx] = acc / (1.f + expf(-acc));  // silu
}

// ---------------- dt = softplus(dt_r @ dtw^T + dtb), K=24 ----------------
__global__ __launch_bounds__(256) void dt_kernel(const float* __restrict__ dbc,
    const float* __restrict__ dtw, const float* __restrict__ dtb, float* __restrict__ dt) {
  int tok = blockIdx.x;
  __shared__ float rr[DTR];
  int t = threadIdx.x;
  if (t < DTR) rr[t] = dbc[(size_t)tok * G + t];
  __syncthreads();
  for (int d = t; d < DI; d += 256) {
    float acc = dtb[d];
#pragma unroll
    for (int k = 0; k < DTR; k++) acc += rr[k] * dtw[d * DTR + k];
    dt[(size_t)tok * DI + d] = (acc > 20.f) ? acc : log1pf(expf(acc));
  }
}

// ---------------- chunked selective scan ----------------
// pass1: per (b, chunk, d): local scan from h=0 over CHL tokens.
//        Writes Aprod[bc][d][n] = prod dA, Sloc[bc][d][n] = local final state.
__global__ __launch_bounds__(256) void scan_pass1(const float* __restrict__ dbc,
    const float* __restrict__ dt, const float* __restrict__ xconv,
    const float* __restrict__ A_log, float* __restrict__ Aprod, float* __restrict__ Sloc) {
  int bc = blockIdx.x;               // b*NCH + c
  int b = bc >> 3, c = bc & (NCH - 1);
  int d = blockIdx.y * 256 + threadIdx.x;
  float Av[DS], h[DS], ap[DS];
#pragma unroll
  for (int n = 0; n < DS; n++) {
    Av[n] = -__expf(A_log[d * DS + n]);
    h[n] = 0.f; ap[n] = 1.f;
  }
  size_t tok0 = (size_t)b * L + c * CHL;
  for (int l = 0; l < CHL; l++) {
    size_t tok = tok0 + l;
    float dtv = dt[tok * DI + d];
    float xcv = xconv[tok * DI + d];
    const float4* Bp = (const float4*)(dbc + tok * G + DTR);
    float dbx = dtv * xcv;
#pragma unroll
    for (int q = 0; q < 4; q++) {
      float4 B4 = Bp[q];
      float dA;
      dA = __expf(dtv * Av[q*4+0]); ap[q*4+0] *= dA; h[q*4+0] = dA * h[q*4+0] + dbx * B4.x;
      dA = __expf(dtv * Av[q*4+1]); ap[q*4+1] *= dA; h[q*4+1] = dA * h[q*4+1] + dbx * B4.y;
      dA = __expf(dtv * Av[q*4+2]); ap[q*4+2] *= dA; h[q*4+2] = dA * h[q*4+2] + dbx * B4.z;
      dA = __expf(dtv * Av[q*4+3]); ap[q*4+3] *= dA; h[q*4+3] = dA * h[q*4+3] + dbx * B4.w;
    }
  }
  float* Ap = Aprod + ((size_t)bc * DI + d) * DS;
  float* Sp = Sloc  + ((size_t)bc * DI + d) * DS;
#pragma unroll
  for (int q = 0; q < 4; q++) {
    *(float4*)(Ap + q * 4) = make_float4(ap[q*4+0], ap[q*4+1], ap[q*4+2], ap[q*4+3]);
    *(float4*)(Sp + q * 4) = make_float4(h[q*4+0], h[q*4+1], h[q*4+2], h[q*4+3]);
  }
}

// pass2: per (b, d, n): serially compose the NCH chunks → Hstart per chunk.
__global__ __launch_bounds__(256) void scan_pass2(const float* __restrict__ Aprod,
    const float* __restrict__ Sloc, float* __restrict__ Hstart) {
  int idx = blockIdx.x * 256 + threadIdx.x;   // b*DI*DS + dn
  int b = idx / (DI * DS);
  int dn = idx - b * DI * DS;
  float h = 0.f;
#pragma unroll
  for (int c = 0; c < NCH; c++) {
    size_t o = ((size_t)(b * NCH + c) * DI) * DS + dn;
    Hstart[o] = h;
    h = Aprod[o] * h + Sloc[o];
  }
}

// pass3: re-scan each chunk from Hstart, emit y with D-skip + silu(z) gate.
__global__ __launch_bounds__(256) void scan_pass3(const float* __restrict__ dbc,
    const float* __restrict__ dt, const float* __restrict__ xconv,
    const float* __restrict__ xz, const float* __restrict__ A_log,
    const float* __restrict__ Dp, const float* __restrict__ Hstart,
    float* __restrict__ y) {
  int bc = blockIdx.x;
  int b = bc >> 3, c = bc & (NCH - 1);
  int d = blockIdx.y * 256 + threadIdx.x;
  float Av[DS], h[DS];
  const float* Hs = Hstart + ((size_t)bc * DI + d) * DS;
#pragma unroll
  for (int n = 0; n < DS; n++) {
    Av[n] = -__expf(A_log[d * DS + n]);
    h[n] = Hs[n];
  }
  float Dv = Dp[d];
  size_t tok0 = (size_t)b * L + c * CHL;
  for (int l = 0; l < CHL; l++) {
    size_t tok = tok0 + l;
    float dtv = dt[tok * DI + d];
    float xcv = xconv[tok * DI + d];
    float zv = xz[tok * (2 * DI) + DI + d];
    const float4* BC = (const float4*)(dbc + tok * G + DTR);
    float dbx = dtv * xcv;
    float p = 0.f;
#pragma unroll
    for (int q = 0; q < 4; q++) {
      float4 B4 = BC[q];
      float4 C4 = BC[q + 4];
      float dA;
      dA = __expf(dtv * Av[q*4+0]); h[q*4+0] = dA * h[q*4+0] + dbx * B4.x; p += h[q*4+0] * C4.x;
      dA = __expf(dtv * Av[q*4+1]); h[q*4+1] = dA * h[q*4+1] + dbx * B4.y; p += h[q*4+1] * C4.y;
      dA = __expf(dtv * Av[q*4+2]); h[q*4+2] = dA * h[q*4+2] + dbx * B4.z; p += h[q*4+2] * C4.z;
      dA = __expf(dtv * Av[q*4+3]); h[q*4+3] = dA * h[q*4+3] + dbx * B4.w; p += h[q*4+3] * C4.w;
    }
    float yv = (p + Dv * xcv) * (zv / (1.f + __expf(-zv)));
    y[tok * DI + d] = yv;
  }
}

// ---------------- masked mean pool ----------------
__global__ __launch_bounds__(128) void pool_kernel(const float* __restrict__ xf,
    const int* __restrict__ ids, float* __restrict__ pooled) {
  int b = blockIdx.x;
  int t = threadIdx.x;  // 0..127, covers 384 in 3 strides
  float cnt = 0.f;
  float sums[3] = {};
  for (int l = 0; l < L; l++) {
    int tok = b * L + l;
    float msk = (ids[tok] != 0) ? 1.f : 0.f;
    cnt += msk;
#pragma unroll
    for (int i = 0; i < 3; i++) sums[i] += msk * xf[(size_t)tok * D + t + i * 128];
  }
  float denom = fmaxf(cnt, 1.f);
#pragma unroll
  for (int i = 0; i < 3; i++) pooled[b * D + t + i * 128] = sums[i] / denom;
}

// ---------------- final proj + L2 normalize ----------------
__global__ __launch_bounds__(256) void proj_norm_kernel(const float* __restrict__ pooled,
    const float* __restrict__ pw, const float* __restrict__ pb, float* __restrict__ out) {
  int b = blockIdx.x;
  int t = threadIdx.x;  // one output per thread (ED=256)
  __shared__ float pr[D];
  __shared__ float red[256];
  for (int i = t; i < D; i += 256) pr[i] = pooled[b * D + i];
  __syncthreads();
  float acc = pb[t];
  for (int k = 0; k < D; k++) acc += pr[k] * pw[t * D + k];
  red[t] = acc * acc;
  __syncthreads();
  for (int s = 128; s > 0; s >>= 1) {
    if (t < s) red[t] += red[t + s];
    __syncthreads();
  }
  float nrm = sqrtf(red[0]);
  float scale = 1.f / fmaxf(nrm, 1e-12f);
  out[b * ED + t] = acc * scale;
}

extern "C" void kernel_launch(void* const* d_in, const int* in_sizes, int n_in,
                              void* d_out, int out_size, void* d_ws, size_t ws_size,
                              hipStream_t stream) {
  const int*   ids  = (const int*)d_in[0];
  const float* emb  = (const float*)d_in[1];
  const float* pos  = (const float*)d_in[2];
  const float* ln_g = (const float*)d_in[3];
  const float* ln_b = (const float*)d_in[4];
  const float* inw  = (const float*)d_in[5];
  const float* cw   = (const float*)d_in[6];
  const float* cb   = (const float*)d_in[7];
  const float* xw   = (const float*)d_in[8];
  const float* dtw  = (const float*)d_in[9];
  const float* dtb  = (const float*)d_in[10];
  const float* Alog = (const float*)d_in[11];
  const float* Dp   = (const float*)d_in[12];
  const float* ow   = (const float*)d_in[13];
  const float* flng = (const float*)d_in[14];
  const float* flnb = (const float*)d_in[15];
  const float* pw   = (const float*)d_in[16];
  const float* pb   = (const float*)d_in[17];
  float* out = (float*)d_out;

  float* ws    = (float*)d_ws;
  float* x     = ws;                        // M*D
  float* xln   = x + (size_t)M * D;         // M*D (dead during scan — reused below)
  float* xz    = xln + (size_t)M * D;       // M*2DI
  float* xconv = xz + (size_t)M * 2 * DI;   // M*DI
  float* dbc   = xconv + (size_t)M * DI;    // M*G
  float* dtb_  = dbc + (size_t)M * G;       // M*DI
  float* ybuf  = dtb_ + (size_t)M * DI;     // M*DI
  float* pooled = ybuf + (size_t)M * DI;    // B*D
  // scan scratch: Aprod/Sloc reuse xln (dead between in_proj GEMM and out_proj GEMM):
  // B*NCH*DI*DS = 4*8*768*16 = 393216 floats each; xln holds M*D = 786432 → fits both.
  float* Aprod = xln;                       // 393216 floats
  float* Sloc  = xln + (size_t)B * NCH * DI * DS;  // 393216 floats
  float* Hstart = pooled + (size_t)B * D;   // 393216 floats appended

  embed_kernel<<<(M * D + 255) / 256, 256, 0, stream>>>(ids, emb, pos, x);

  for (int i = 0; i < NL; i++) {
    layernorm_kernel<<<M, 64, 0, stream>>>(x, ln_g + i * D, ln_b + i * D, xln);

    dim3 g1(M / 64, (2 * DI) / 64);
    gemm_kernel<0><<<g1, 256, 0, stream>>>(xln, inw + (size_t)i * 2 * DI * D, xz, M, 2 * DI, D);

    conv_silu_kernel<<<(M * DI + 255) / 256, 256, 0, stream>>>(
        xz, cw + (size_t)i * DI * DC, cb + (size_t)i * DI, xconv);

    dim3 g2(M / 64, (G + 63) / 64);
    gemm_kernel<0><<<g2, 256, 0, stream>>>(xconv, xw + (size_t)i * G * DI, dbc, M, G, DI);

    dt_kernel<<<M, 256, 0, stream>>>(dbc, dtw + (size_t)i * DI * DTR, dtb + (size_t)i * DI, dtb_);

    dim3 gs(B * NCH, DI / 256);
    scan_pass1<<<gs, 256, 0, stream>>>(dbc, dtb_, xconv,
        Alog + (size_t)i * DI * DS, Aprod, Sloc);
    scan_pass2<<<(B * DI * DS) / 256, 256, 0, stream>>>(Aprod, Sloc, Hstart);
    scan_pass3<<<gs, 256, 0, stream>>>(dbc, dtb_, xconv, xz,
        Alog + (size_t)i * DI * DS, Dp + (size_t)i * DI, Hstart, ybuf);

    dim3 g3(M / 64, D / 64);
    gemm_kernel<1><<<g3, 256, 0, stream>>>(ybuf, ow + (size_t)i * D * DI, x, M, D, DI);
  }

  layernorm_kernel<<<M, 64, 0, stream>>>(x, flng, flnb, xln);
  pool_kernel<<<B, 128, 0, stream>>>(xln, ids, pooled);
  proj_norm_kernel<<<B, ED, 0, stream>>>(pooled, pw, pb, out);
}

// Round 7
// 1872.288 us; speedup vs baseline: 2.6938x; 1.3034x over previous
//
#include <hip/hip_runtime.h>
#include <hip/hip_bf16.h>
#include <math.h>

#define B 4
#define L 512
#define D 384
#define NL 8
#define DS 16
#define DC 4
#define DI 768
#define DTR 24
#define G (DTR + 2*DS)   // 56
#define ED 256
#define M (B*L)          // 2048
#define NCH 8            // chunks along L
#define CHL (L/NCH)      // 64 tokens per chunk

typedef __attribute__((ext_vector_type(8))) short short8;
typedef __attribute__((ext_vector_type(4))) float f32x4;

// pack two floats -> two bf16 (RNE) in one uint
__device__ inline unsigned bf2(float a, float b) {
  unsigned ua = __float_as_uint(a), ub = __float_as_uint(b);
  ua = (ua + 0x7FFFu + ((ua >> 16) & 1u)) >> 16;
  ub = (ub + 0x7FFFu + ((ub >> 16) & 1u)) >> 16;
  return (ua & 0xFFFFu) | (ub << 16);
}

// ---------------- embed: x = emb[ids] + pos ----------------
__global__ __launch_bounds__(256) void embed_kernel(const int* __restrict__ ids,
    const float* __restrict__ emb, const float* __restrict__ pos, float* __restrict__ x) {
  int idx = blockIdx.x * 256 + threadIdx.x;
  if (idx >= M * D) return;
  int m = idx / D, d = idx - m * D;
  int l = m & (L - 1);
  x[idx] = emb[(size_t)ids[m] * D + d] + pos[l * D + d];
}

// ---------------- layernorm: one wave per row of D=384 ----------------
__global__ __launch_bounds__(64) void layernorm_kernel(const float* __restrict__ x,
    const float* __restrict__ g, const float* __restrict__ b, float* __restrict__ o) {
  int row = blockIdx.x;
  int t = threadIdx.x;
  const float* xr = x + (size_t)row * D;
  float v[6];
  float s = 0.f;
#pragma unroll
  for (int i = 0; i < 6; i++) { v[i] = xr[t + i * 64]; s += v[i]; }
#pragma unroll
  for (int o_ = 32; o_ > 0; o_ >>= 1) s += __shfl_xor(s, o_);
  float mean = s * (1.0f / D);
  float vs = 0.f;
#pragma unroll
  for (int i = 0; i < 6; i++) { float dd = v[i] - mean; vs += dd * dd; }
#pragma unroll
  for (int o_ = 32; o_ > 0; o_ >>= 1) vs += __shfl_xor(vs, o_);
  float inv = 1.0f / sqrtf(vs * (1.0f / D) + 1e-5f);
  float* orow = o + (size_t)row * D;
#pragma unroll
  for (int i = 0; i < 6; i++) {
    int d = t + i * 64;
    orow[d] = (v[i] - mean) * inv * g[d] + b[d];
  }
}

// ---------------- bf16 MFMA GEMM: C[M,N] = A[M,K] @ W[N,K]^T (+C if ADD) ----
// fp32 inputs converted to bf16 during LDS staging; fp32 accumulate.
// 128x128 tile, BK=64, 256 threads = 4 waves, each wave a 64x64 quadrant.
// LDS: 16B slots, XOR-swizzled (slot ^ row&7) for conflict-free frag reads.
// Requires: Mm % 128 == 0, Kk % 64 == 0. Nn arbitrary (B rows zero-padded).
template <int ADD>
__global__ __launch_bounds__(256) void gemm_bf16_kernel(const float* __restrict__ A,
    const float* __restrict__ W, float* __restrict__ C, int Mm, int Nn, int Kk) {
  __shared__ uint4 As[1024];   // 128 rows x 8 slots
  __shared__ uint4 Bs[1024];
  int t = threadIdx.x;
  int lane = t & 63, w = t >> 6;
  int wm = (w >> 1) * 64, wn = (w & 1) * 64;
  int m0 = blockIdx.x * 128, n0 = blockIdx.y * 128;

  f32x4 acc[4][4] = {};

  int srow = t >> 1;           // 0..127
  int sb = (t & 1) * 4;        // 0 or 4
  const int rA = m0 + srow;
  const int rB = n0 + srow;
  const bool bok = rB < Nn;

  for (int k0 = 0; k0 < Kk; k0 += 64) {
    const float* Ag = A + (size_t)rA * Kk + k0 + sb * 8;
    const float* Wg = W + (size_t)rB * Kk + k0 + sb * 8;
    uint4 av[4], bv[4];
#pragma unroll
    for (int s = 0; s < 4; s++) {
      float4 lo = *(const float4*)(Ag + s * 8);
      float4 hi = *(const float4*)(Ag + s * 8 + 4);
      av[s] = make_uint4(bf2(lo.x, lo.y), bf2(lo.z, lo.w), bf2(hi.x, hi.y), bf2(hi.z, hi.w));
      if (bok) {
        float4 wl = *(const float4*)(Wg + s * 8);
        float4 wh = *(const float4*)(Wg + s * 8 + 4);
        bv[s] = make_uint4(bf2(wl.x, wl.y), bf2(wl.z, wl.w), bf2(wh.x, wh.y), bf2(wh.z, wh.w));
      } else {
        bv[s] = make_uint4(0u, 0u, 0u, 0u);
      }
    }
    __syncthreads();   // previous iteration's LDS reads done
#pragma unroll
    for (int s = 0; s < 4; s++) {
      As[srow * 8 + ((sb + s) ^ (srow & 7))] = av[s];
      Bs[srow * 8 + ((sb + s) ^ (srow & 7))] = bv[s];
    }
    __syncthreads();
#pragma unroll
    for (int kk = 0; kk < 2; kk++) {
      int ks = kk * 4 + (lane >> 4);     // k-slot index within row
      short8 af[4], bfv[4];
#pragma unroll
      for (int i = 0; i < 4; i++) {
        int ra = wm + i * 16 + (lane & 15);
        af[i] = *(short8*)&As[ra * 8 + (ks ^ (ra & 7))];
        int rb = wn + i * 16 + (lane & 15);
        bfv[i] = *(short8*)&Bs[rb * 8 + (ks ^ (rb & 7))];
      }
#pragma unroll
      for (int i = 0; i < 4; i++)
#pragma unroll
        for (int j = 0; j < 4; j++)
          acc[i][j] = __builtin_amdgcn_mfma_f32_16x16x32_bf16(af[i], bfv[j], acc[i][j], 0, 0, 0);
    }
  }

  // C/D layout: col = lane&15, row = (lane>>4)*4 + reg
#pragma unroll
  for (int i = 0; i < 4; i++) {
    int cm = m0 + wm + i * 16 + (lane >> 4) * 4;
#pragma unroll
    for (int j = 0; j < 4; j++) {
      int cn = n0 + wn + j * 16 + (lane & 15);
      if (cn >= Nn) continue;
#pragma unroll
      for (int r = 0; r < 4; r++) {
        size_t off = (size_t)(cm + r) * Nn + cn;
        float v = acc[i][j][r];
        if (ADD) v += C[off];
        C[off] = v;
      }
    }
  }
}

// ---------------- causal conv (DC=4) + silu ----------------
__global__ __launch_bounds__(256) void conv_silu_kernel(const float* __restrict__ xz,
    const float* __restrict__ cw, const float* __restrict__ cb, float* __restrict__ xc) {
  int idx = blockIdx.x * 256 + threadIdx.x;
  if (idx >= M * DI) return;
  int m = idx / DI, e = idx - m * DI;
  int l = m & (L - 1);
  float acc = cb[e];
#pragma unroll
  for (int k = 0; k < DC; k++) {
    int ll = l - (DC - 1) + k;
    if (ll >= 0) acc += xz[(size_t)(m - (DC - 1) + k) * (2 * DI) + e] * cw[e * DC + k];
  }
  xc[idx] = acc / (1.f + expf(-acc));  // silu
}

// ---------------- dt = softplus(dt_r @ dtw^T + dtb), K=24 ----------------
__global__ __launch_bounds__(256) void dt_kernel(const float* __restrict__ dbc,
    const float* __restrict__ dtw, const float* __restrict__ dtb, float* __restrict__ dt) {
  int tok = blockIdx.x;
  __shared__ float rr[DTR];
  int t = threadIdx.x;
  if (t < DTR) rr[t] = dbc[(size_t)tok * G + t];
  __syncthreads();
  for (int d = t; d < DI; d += 256) {
    float acc = dtb[d];
#pragma unroll
    for (int k = 0; k < DTR; k++) acc += rr[k] * dtw[d * DTR + k];
    dt[(size_t)tok * DI + d] = (acc > 20.f) ? acc : log1pf(expf(acc));
  }
}

// ---------------- chunked selective scan ----------------
__global__ __launch_bounds__(256) void scan_pass1(const float* __restrict__ dbc,
    const float* __restrict__ dt, const float* __restrict__ xconv,
    const float* __restrict__ A_log, float* __restrict__ Aprod, float* __restrict__ Sloc) {
  int bc = blockIdx.x;               // b*NCH + c
  int b = bc >> 3, c = bc & (NCH - 1);
  int d = blockIdx.y * 256 + threadIdx.x;
  float Av[DS], h[DS], ap[DS];
#pragma unroll
  for (int n = 0; n < DS; n++) {
    Av[n] = -__expf(A_log[d * DS + n]);
    h[n] = 0.f; ap[n] = 1.f;
  }
  size_t tok0 = (size_t)b * L + c * CHL;
  for (int l = 0; l < CHL; l++) {
    size_t tok = tok0 + l;
    float dtv = dt[tok * DI + d];
    float xcv = xconv[tok * DI + d];
    const float4* Bp = (const float4*)(dbc + tok * G + DTR);
    float dbx = dtv * xcv;
#pragma unroll
    for (int q = 0; q < 4; q++) {
      float4 B4 = Bp[q];
      float dA;
      dA = __expf(dtv * Av[q*4+0]); ap[q*4+0] *= dA; h[q*4+0] = dA * h[q*4+0] + dbx * B4.x;
      dA = __expf(dtv * Av[q*4+1]); ap[q*4+1] *= dA; h[q*4+1] = dA * h[q*4+1] + dbx * B4.y;
      dA = __expf(dtv * Av[q*4+2]); ap[q*4+2] *= dA; h[q*4+2] = dA * h[q*4+2] + dbx * B4.z;
      dA = __expf(dtv * Av[q*4+3]); ap[q*4+3] *= dA; h[q*4+3] = dA * h[q*4+3] + dbx * B4.w;
    }
  }
  float* Ap = Aprod + ((size_t)bc * DI + d) * DS;
  float* Sp = Sloc  + ((size_t)bc * DI + d) * DS;
#pragma unroll
  for (int q = 0; q < 4; q++) {
    *(float4*)(Ap + q * 4) = make_float4(ap[q*4+0], ap[q*4+1], ap[q*4+2], ap[q*4+3]);
    *(float4*)(Sp + q * 4) = make_float4(h[q*4+0], h[q*4+1], h[q*4+2], h[q*4+3]);
  }
}

__global__ __launch_bounds__(256) void scan_pass2(const float* __restrict__ Aprod,
    const float* __restrict__ Sloc, float* __restrict__ Hstart) {
  int idx = blockIdx.x * 256 + threadIdx.x;   // b*DI*DS + dn
  int b = idx / (DI * DS);
  int dn = idx - b * DI * DS;
  float h = 0.f;
#pragma unroll
  for (int c = 0; c < NCH; c++) {
    size_t o = ((size_t)(b * NCH + c) * DI) * DS + dn;
    Hstart[o] = h;
    h = Aprod[o] * h + Sloc[o];
  }
}

__global__ __launch_bounds__(256) void scan_pass3(const float* __restrict__ dbc,
    const float* __restrict__ dt, const float* __restrict__ xconv,
    const float* __restrict__ xz, const float* __restrict__ A_log,
    const float* __restrict__ Dp, const float* __restrict__ Hstart,
    float* __restrict__ y) {
  int bc = blockIdx.x;
  int b = bc >> 3, c = bc & (NCH - 1);
  int d = blockIdx.y * 256 + threadIdx.x;
  float Av[DS], h[DS];
  const float* Hs = Hstart + ((size_t)bc * DI + d) * DS;
#pragma unroll
  for (int n = 0; n < DS; n++) {
    Av[n] = -__expf(A_log[d * DS + n]);
    h[n] = Hs[n];
  }
  float Dv = Dp[d];
  size_t tok0 = (size_t)b * L + c * CHL;
  for (int l = 0; l < CHL; l++) {
    size_t tok = tok0 + l;
    float dtv = dt[tok * DI + d];
    float xcv = xconv[tok * DI + d];
    float zv = xz[tok * (2 * DI) + DI + d];
    const float4* BC = (const float4*)(dbc + tok * G + DTR);
    float dbx = dtv * xcv;
    float p = 0.f;
#pragma unroll
    for (int q = 0; q < 4; q++) {
      float4 B4 = BC[q];
      float4 C4 = BC[q + 4];
      float dA;
      dA = __expf(dtv * Av[q*4+0]); h[q*4+0] = dA * h[q*4+0] + dbx * B4.x; p += h[q*4+0] * C4.x;
      dA = __expf(dtv * Av[q*4+1]); h[q*4+1] = dA * h[q*4+1] + dbx * B4.y; p += h[q*4+1] * C4.y;
      dA = __expf(dtv * Av[q*4+2]); h[q*4+2] = dA * h[q*4+2] + dbx * B4.z; p += h[q*4+2] * C4.z;
      dA = __expf(dtv * Av[q*4+3]); h[q*4+3] = dA * h[q*4+3] + dbx * B4.w; p += h[q*4+3] * C4.w;
    }
    float yv = (p + Dv * xcv) * (zv / (1.f + __expf(-zv)));
    y[tok * DI + d] = yv;
  }
}

// ---------------- masked mean pool ----------------
__global__ __launch_bounds__(128) void pool_kernel(const float* __restrict__ xf,
    const int* __restrict__ ids, float* __restrict__ pooled) {
  int b = blockIdx.x;
  int t = threadIdx.x;
  float cnt = 0.f;
  float sums[3] = {};
  for (int l = 0; l < L; l++) {
    int tok = b * L + l;
    float msk = (ids[tok] != 0) ? 1.f : 0.f;
    cnt += msk;
#pragma unroll
    for (int i = 0; i < 3; i++) sums[i] += msk * xf[(size_t)tok * D + t + i * 128];
  }
  float denom = fmaxf(cnt, 1.f);
#pragma unroll
  for (int i = 0; i < 3; i++) pooled[b * D + t + i * 128] = sums[i] / denom;
}

// ---------------- final proj + L2 normalize ----------------
__global__ __launch_bounds__(256) void proj_norm_kernel(const float* __restrict__ pooled,
    const float* __restrict__ pw, const float* __restrict__ pb, float* __restrict__ out) {
  int b = blockIdx.x;
  int t = threadIdx.x;
  __shared__ float pr[D];
  __shared__ float red[256];
  for (int i = t; i < D; i += 256) pr[i] = pooled[b * D + i];
  __syncthreads();
  float acc = pb[t];
  for (int k = 0; k < D; k++) acc += pr[k] * pw[t * D + k];
  red[t] = acc * acc;
  __syncthreads();
  for (int s = 128; s > 0; s >>= 1) {
    if (t < s) red[t] += red[t + s];
    __syncthreads();
  }
  float nrm = sqrtf(red[0]);
  float scale = 1.f / fmaxf(nrm, 1e-12f);
  out[b * ED + t] = acc * scale;
}

extern "C" void kernel_launch(void* const* d_in, const int* in_sizes, int n_in,
                              void* d_out, int out_size, void* d_ws, size_t ws_size,
                              hipStream_t stream) {
  const int*   ids  = (const int*)d_in[0];
  const float* emb  = (const float*)d_in[1];
  const float* pos  = (const float*)d_in[2];
  const float* ln_g = (const float*)d_in[3];
  const float* ln_b = (const float*)d_in[4];
  const float* inw  = (const float*)d_in[5];
  const float* cw   = (const float*)d_in[6];
  const float* cb   = (const float*)d_in[7];
  const float* xw   = (const float*)d_in[8];
  const float* dtw  = (const float*)d_in[9];
  const float* dtb  = (const float*)d_in[10];
  const float* Alog = (const float*)d_in[11];
  const float* Dp   = (const float*)d_in[12];
  const float* ow   = (const float*)d_in[13];
  const float* flng = (const float*)d_in[14];
  const float* flnb = (const float*)d_in[15];
  const float* pw   = (const float*)d_in[16];
  const float* pb   = (const float*)d_in[17];
  float* out = (float*)d_out;

  float* ws    = (float*)d_ws;
  float* x     = ws;                        // M*D
  float* xln   = x + (size_t)M * D;         // M*D (dead during scan — reused below)
  float* xz    = xln + (size_t)M * D;       // M*2DI
  float* xconv = xz + (size_t)M * 2 * DI;   // M*DI
  float* dbc   = xconv + (size_t)M * DI;    // M*G
  float* dtb_  = dbc + (size_t)M * G;       // M*DI
  float* ybuf  = dtb_ + (size_t)M * DI;     // M*DI
  float* pooled = ybuf + (size_t)M * DI;    // B*D
  float* Aprod = xln;                       // 393216 floats (reuse xln)
  float* Sloc  = xln + (size_t)B * NCH * DI * DS;
  float* Hstart = pooled + (size_t)B * D;   // 393216 floats

  embed_kernel<<<(M * D + 255) / 256, 256, 0, stream>>>(ids, emb, pos, x);

  for (int i = 0; i < NL; i++) {
    layernorm_kernel<<<M, 64, 0, stream>>>(x, ln_g + i * D, ln_b + i * D, xln);

    dim3 g1(M / 128, (2 * DI) / 128);   // 16 x 12
    gemm_bf16_kernel<0><<<g1, 256, 0, stream>>>(xln, inw + (size_t)i * 2 * DI * D, xz, M, 2 * DI, D);

    conv_silu_kernel<<<(M * DI + 255) / 256, 256, 0, stream>>>(
        xz, cw + (size_t)i * DI * DC, cb + (size_t)i * DI, xconv);

    dim3 g2(M / 128, (G + 127) / 128);  // 16 x 1 (N=56, padded)
    gemm_bf16_kernel<0><<<g2, 256, 0, stream>>>(xconv, xw + (size_t)i * G * DI, dbc, M, G, DI);

    dt_kernel<<<M, 256, 0, stream>>>(dbc, dtw + (size_t)i * DI * DTR, dtb + (size_t)i * DI, dtb_);

    dim3 gs(B * NCH, DI / 256);
    scan_pass1<<<gs, 256, 0, stream>>>(dbc, dtb_, xconv,
        Alog + (size_t)i * DI * DS, Aprod, Sloc);
    scan_pass2<<<(B * DI * DS) / 256, 256, 0, stream>>>(Aprod, Sloc, Hstart);
    scan_pass3<<<gs, 256, 0, stream>>>(dbc, dtb_, xconv, xz,
        Alog + (size_t)i * DI * DS, Dp + (size_t)i * DI, Hstart, ybuf);

    dim3 g3(M / 128, D / 128);          // 16 x 3
    gemm_bf16_kernel<1><<<g3, 256, 0, stream>>>(ybuf, ow + (size_t)i * D * DI, x, M, D, DI);
  }

  layernorm_kernel<<<M, 64, 0, stream>>>(x, flng, flnb, xln);
  pool_kernel<<<B, 128, 0, stream>>>(xln, ids, pooled);
  proj_norm_kernel<<<B, ED, 0, stream>>>(pooled, pw, pb, out);
}

// Round 10
// 1394.392 us; speedup vs baseline: 3.6171x; 1.3427x over previous
//
#include <hip/hip_runtime.h>
#include <hip/hip_bf16.h>
#include <math.h>

#define B 4
#define L 512
#define D 384
#define NL 8
#define DS 16
#define DC 4
#define DI 768
#define DTR 24
#define G (DTR + 2*DS)   // 56
#define ED 256
#define M (B*L)          // 2048
#define NCH 8            // chunks along L
#define CHL (L/NCH)      // 64 tokens per chunk

typedef __attribute__((ext_vector_type(8))) short short8;
typedef __attribute__((ext_vector_type(4))) float f32x4;
typedef unsigned short ushort_t;

// pack two floats -> two bf16 (RNE) in one uint
__device__ inline unsigned bf2(float a, float b) {
  unsigned ua = __float_as_uint(a), ub = __float_as_uint(b);
  ua = (ua + 0x7FFFu + ((ua >> 16) & 1u)) >> 16;
  ub = (ub + 0x7FFFu + ((ub >> 16) & 1u)) >> 16;
  return (ua & 0xFFFFu) | (ub << 16);
}
__device__ inline ushort_t bf1(float a) {
  unsigned u = __float_as_uint(a);
  u = (u + 0x7FFFu + ((u >> 16) & 1u)) >> 16;
  return (ushort_t)u;
}

// ---------------- fp32 -> bf16 bulk convert (n8 = n/8) ----------------
__global__ __launch_bounds__(256) void f2bf_kernel(const float* __restrict__ in,
    ushort_t* __restrict__ out, int n8) {
  int i = blockIdx.x * 256 + threadIdx.x;
  if (i >= n8) return;
  float4 a = *(const float4*)(in + (size_t)i * 8);
  float4 b = *(const float4*)(in + (size_t)i * 8 + 4);
  *(uint4*)(out + (size_t)i * 8) =
      make_uint4(bf2(a.x, a.y), bf2(a.z, a.w), bf2(b.x, b.y), bf2(b.z, b.w));
}

// ---------------- embed: x = emb[ids] + pos ----------------
__global__ __launch_bounds__(256) void embed_kernel(const int* __restrict__ ids,
    const float* __restrict__ emb, const float* __restrict__ pos, float* __restrict__ x) {
  int idx = blockIdx.x * 256 + threadIdx.x;
  if (idx >= M * D) return;
  int m = idx / D, d = idx - m * D;
  int l = m & (L - 1);
  x[idx] = emb[(size_t)ids[m] * D + d] + pos[l * D + d];
}

// ---------------- layernorm: one wave per row; writes fp32 + bf16 ----------
__global__ __launch_bounds__(64) void layernorm_kernel(const float* __restrict__ x,
    const float* __restrict__ g, const float* __restrict__ b,
    float* __restrict__ o, ushort_t* __restrict__ obf) {
  int row = blockIdx.x;
  int t = threadIdx.x;
  const float* xr = x + (size_t)row * D;
  float v[6];
  float s = 0.f;
#pragma unroll
  for (int i = 0; i < 6; i++) { v[i] = xr[t + i * 64]; s += v[i]; }
#pragma unroll
  for (int o_ = 32; o_ > 0; o_ >>= 1) s += __shfl_xor(s, o_);
  float mean = s * (1.0f / D);
  float vs = 0.f;
#pragma unroll
  for (int i = 0; i < 6; i++) { float dd = v[i] - mean; vs += dd * dd; }
#pragma unroll
  for (int o_ = 32; o_ > 0; o_ >>= 1) vs += __shfl_xor(vs, o_);
  float inv = 1.0f / sqrtf(vs * (1.0f / D) + 1e-5f);
  float* orow = o + (size_t)row * D;
  ushort_t* brow = obf + (size_t)row * D;
#pragma unroll
  for (int i = 0; i < 6; i++) {
    int d = t + i * 64;
    float val = (v[i] - mean) * inv * g[d] + b[d];
    orow[d] = val;
    brow[d] = bf1(val);
  }
}

// ---------------- bf16 MFMA GEMM: C[M,N] = A[M,K] @ W[N,K]^T (+C if ADD) ----
// A, W already bf16. Tile 32(M) x 64(N), BK=64, 128 threads = 2 waves.
// Wave w owns N-half w*32. LDS 16B slots XOR-swizzled (slot ^ row&7): 0 conflicts
// (measured R7). Requires Mm%32==0, Kk%64==0; Nn arbitrary (zero-pad + guard).
template <int ADD>
__global__ __launch_bounds__(128) void gemm_bt_kernel(const ushort_t* __restrict__ A,
    const ushort_t* __restrict__ W, float* __restrict__ C, int Mm, int Nn, int Kk) {
  __shared__ uint4 As[32 * 8];   // 4 KB
  __shared__ uint4 Bs[64 * 8];   // 8 KB
  int t = threadIdx.x;
  int lane = t & 63, w = t >> 6;
  int m0 = blockIdx.x * 32, n0 = blockIdx.y * 64;

  f32x4 acc[2][2] = {};

  // staging map: thread t covers A slots {t, t+128}, B slots {t, t+128, t+256, t+384}
  for (int k0 = 0; k0 < Kk; k0 += 64) {
    uint4 av[2], bv[4];
#pragma unroll
    for (int u = 0; u < 2; u++) {
      int q = t + u * 128;
      int row = q >> 3, p = q & 7;
      av[u] = *(const uint4*)(A + (size_t)(m0 + row) * Kk + k0 + ((p ^ (row & 7)) << 3));
    }
#pragma unroll
    for (int u = 0; u < 4; u++) {
      int q = t + u * 128;
      int row = q >> 3, p = q & 7;
      int grow = n0 + row;
      if (grow < Nn)
        bv[u] = *(const uint4*)(W + (size_t)grow * Kk + k0 + ((p ^ (row & 7)) << 3));
      else
        bv[u] = make_uint4(0u, 0u, 0u, 0u);
    }
    __syncthreads();   // previous iteration's LDS reads done
#pragma unroll
    for (int u = 0; u < 2; u++) As[t + u * 128] = av[u];
#pragma unroll
    for (int u = 0; u < 4; u++) Bs[t + u * 128] = bv[u];
    __syncthreads();
#pragma unroll
    for (int kk = 0; kk < 2; kk++) {
      int ks = kk * 4 + (lane >> 4);
      short8 af[2], bfv[2];
#pragma unroll
      for (int i = 0; i < 2; i++) {
        int ra = i * 16 + (lane & 15);
        af[i] = *(short8*)&As[ra * 8 + (ks ^ (ra & 7))];
      }
#pragma unroll
      for (int j = 0; j < 2; j++) {
        int rb = w * 32 + j * 16 + (lane & 15);
        bfv[j] = *(short8*)&Bs[rb * 8 + (ks ^ (rb & 7))];
      }
#pragma unroll
      for (int i = 0; i < 2; i++)
#pragma unroll
        for (int j = 0; j < 2; j++)
          acc[i][j] = __builtin_amdgcn_mfma_f32_16x16x32_bf16(af[i], bfv[j], acc[i][j], 0, 0, 0);
    }
  }

  // C/D layout: col = lane&15, row = (lane>>4)*4 + reg
#pragma unroll
  for (int i = 0; i < 2; i++) {
    int cm = m0 + i * 16 + (lane >> 4) * 4;
#pragma unroll
    for (int j = 0; j < 2; j++) {
      int cn = n0 + w * 32 + j * 16 + (lane & 15);
      if (cn >= Nn) continue;
#pragma unroll
      for (int r = 0; r < 4; r++) {
        size_t off = (size_t)(cm + r) * Nn + cn;
        float v = acc[i][j][r];
        if (ADD) v += C[off];
        C[off] = v;
      }
    }
  }
}

// ---------------- causal conv (DC=4) + silu; writes fp32 + bf16 ----------
__global__ __launch_bounds__(256) void conv_silu_kernel(const float* __restrict__ xz,
    const float* __restrict__ cw, const float* __restrict__ cb,
    float* __restrict__ xc, ushort_t* __restrict__ xcbf) {
  int idx = blockIdx.x * 256 + threadIdx.x;
  if (idx >= M * DI) return;
  int m = idx / DI, e = idx - m * DI;
  int l = m & (L - 1);
  float acc = cb[e];
#pragma unroll
  for (int k = 0; k < DC; k++) {
    int ll = l - (DC - 1) + k;
    if (ll >= 0) acc += xz[(size_t)(m - (DC - 1) + k) * (2 * DI) + e] * cw[e * DC + k];
  }
  float sv = acc / (1.f + __expf(-acc));  // silu
  xc[idx] = sv;
  xcbf[idx] = bf1(sv);
}

// ---------------- dt = softplus(dt_r @ dtw^T + dtb), K=24 ----------------
__global__ __launch_bounds__(256) void dt_kernel(const float* __restrict__ dbc,
    const float* __restrict__ dtw, const float* __restrict__ dtb, float* __restrict__ dt) {
  int tok = blockIdx.x;
  __shared__ float rr[DTR];
  int t = threadIdx.x;
  if (t < DTR) rr[t] = dbc[(size_t)tok * G + t];
  __syncthreads();
  for (int d = t; d < DI; d += 256) {
    float acc = dtb[d];
#pragma unroll
    for (int k = 0; k < DTR; k++) acc += rr[k] * dtw[d * DTR + k];
    dt[(size_t)tok * DI + d] = (acc > 20.f) ? acc : log1pf(expf(acc));
  }
}

// ---------------- chunked selective scan ----------------
__global__ __launch_bounds__(256) void scan_pass1(const float* __restrict__ dbc,
    const float* __restrict__ dt, const float* __restrict__ xconv,
    const float* __restrict__ A_log, float* __restrict__ Aprod, float* __restrict__ Sloc) {
  int bc = blockIdx.x;               // b*NCH + c
  int b = bc >> 3, c = bc & (NCH - 1);
  int d = blockIdx.y * 256 + threadIdx.x;
  float Av[DS], h[DS], ap[DS];
#pragma unroll
  for (int n = 0; n < DS; n++) {
    Av[n] = -__expf(A_log[d * DS + n]);
    h[n] = 0.f; ap[n] = 1.f;
  }
  size_t tok0 = (size_t)b * L + c * CHL;
  for (int l = 0; l < CHL; l++) {
    size_t tok = tok0 + l;
    float dtv = dt[tok * DI + d];
    float xcv = xconv[tok * DI + d];
    const float4* Bp = (const float4*)(dbc + tok * G + DTR);
    float dbx = dtv * xcv;
#pragma unroll
    for (int q = 0; q < 4; q++) {
      float4 B4 = Bp[q];
      float dA;
      dA = __expf(dtv * Av[q*4+0]); ap[q*4+0] *= dA; h[q*4+0] = dA * h[q*4+0] + dbx * B4.x;
      dA = __expf(dtv * Av[q*4+1]); ap[q*4+1] *= dA; h[q*4+1] = dA * h[q*4+1] + dbx * B4.y;
      dA = __expf(dtv * Av[q*4+2]); ap[q*4+2] *= dA; h[q*4+2] = dA * h[q*4+2] + dbx * B4.z;
      dA = __expf(dtv * Av[q*4+3]); ap[q*4+3] *= dA; h[q*4+3] = dA * h[q*4+3] + dbx * B4.w;
    }
  }
  float* Ap = Aprod + ((size_t)bc * DI + d) * DS;
  float* Sp = Sloc  + ((size_t)bc * DI + d) * DS;
#pragma unroll
  for (int q = 0; q < 4; q++) {
    *(float4*)(Ap + q * 4) = make_float4(ap[q*4+0], ap[q*4+1], ap[q*4+2], ap[q*4+3]);
    *(float4*)(Sp + q * 4) = make_float4(h[q*4+0], h[q*4+1], h[q*4+2], h[q*4+3]);
  }
}

__global__ __launch_bounds__(256) void scan_pass2(const float* __restrict__ Aprod,
    const float* __restrict__ Sloc, float* __restrict__ Hstart) {
  int idx = blockIdx.x * 256 + threadIdx.x;   // b*DI*DS + dn
  int b = idx / (DI * DS);
  int dn = idx - b * DI * DS;
  float h = 0.f;
#pragma unroll
  for (int c = 0; c < NCH; c++) {
    size_t o = ((size_t)(b * NCH + c) * DI) * DS + dn;
    Hstart[o] = h;
    h = Aprod[o] * h + Sloc[o];
  }
}

// pass3 writes bf16 y (only the out_proj GEMM consumes it)
__global__ __launch_bounds__(256) void scan_pass3(const float* __restrict__ dbc,
    const float* __restrict__ dt, const float* __restrict__ xconv,
    const float* __restrict__ xz, const float* __restrict__ A_log,
    const float* __restrict__ Dp, const float* __restrict__ Hstart,
    ushort_t* __restrict__ y) {
  int bc = blockIdx.x;
  int b = bc >> 3, c = bc & (NCH - 1);
  int d = blockIdx.y * 256 + threadIdx.x;
  float Av[DS], h[DS];
  const float* Hs = Hstart + ((size_t)bc * DI + d) * DS;
#pragma unroll
  for (int n = 0; n < DS; n++) {
    Av[n] = -__expf(A_log[d * DS + n]);
    h[n] = Hs[n];
  }
  float Dv = Dp[d];
  size_t tok0 = (size_t)b * L + c * CHL;
  for (int l = 0; l < CHL; l++) {
    size_t tok = tok0 + l;
    float dtv = dt[tok * DI + d];
    float xcv = xconv[tok * DI + d];
    float zv = xz[tok * (2 * DI) + DI + d];
    const float4* BC = (const float4*)(dbc + tok * G + DTR);
    float dbx = dtv * xcv;
    float p = 0.f;
#pragma unroll
    for (int q = 0; q < 4; q++) {
      float4 B4 = BC[q];
      float4 C4 = BC[q + 4];
      float dA;
      dA = __expf(dtv * Av[q*4+0]); h[q*4+0] = dA * h[q*4+0] + dbx * B4.x; p += h[q*4+0] * C4.x;
      dA = __expf(dtv * Av[q*4+1]); h[q*4+1] = dA * h[q*4+1] + dbx * B4.y; p += h[q*4+1] * C4.y;
      dA = __expf(dtv * Av[q*4+2]); h[q*4+2] = dA * h[q*4+2] + dbx * B4.z; p += h[q*4+2] * C4.z;
      dA = __expf(dtv * Av[q*4+3]); h[q*4+3] = dA * h[q*4+3] + dbx * B4.w; p += h[q*4+3] * C4.w;
    }
    float yv = (p + Dv * xcv) * (zv / (1.f + __expf(-zv)));
    y[tok * DI + d] = bf1(yv);
  }
}

// ---------------- masked mean pool ----------------
__global__ __launch_bounds__(128) void pool_kernel(const float* __restrict__ xf,
    const int* __restrict__ ids, float* __restrict__ pooled) {
  int b = blockIdx.x;
  int t = threadIdx.x;
  float cnt = 0.f;
  float sums[3] = {};
  for (int l = 0; l < L; l++) {
    int tok = b * L + l;
    float msk = (ids[tok] != 0) ? 1.f : 0.f;
    cnt += msk;
#pragma unroll
    for (int i = 0; i < 3; i++) sums[i] += msk * xf[(size_t)tok * D + t + i * 128];
  }
  float denom = fmaxf(cnt, 1.f);
#pragma unroll
  for (int i = 0; i < 3; i++) pooled[b * D + t + i * 128] = sums[i] / denom;
}

// ---------------- final proj + L2 normalize ----------------
__global__ __launch_bounds__(256) void proj_norm_kernel(const float* __restrict__ pooled,
    const float* __restrict__ pw, const float* __restrict__ pb, float* __restrict__ out) {
  int b = blockIdx.x;
  int t = threadIdx.x;
  __shared__ float pr[D];
  __shared__ float red[256];
  for (int i = t; i < D; i += 256) pr[i] = pooled[b * D + i];
  __syncthreads();
  float acc = pb[t];
  for (int k = 0; k < D; k++) acc += pr[k] * pw[t * D + k];
  red[t] = acc * acc;
  __syncthreads();
  for (int s = 128; s > 0; s >>= 1) {
    if (t < s) red[t] += red[t + s];
    __syncthreads();
  }
  float nrm = sqrtf(red[0]);
  float scale = 1.f / fmaxf(nrm, 1e-12f);
  out[b * ED + t] = acc * scale;
}

extern "C" void kernel_launch(void* const* d_in, const int* in_sizes, int n_in,
                              void* d_out, int out_size, void* d_ws, size_t ws_size,
                              hipStream_t stream) {
  const int*   ids  = (const int*)d_in[0];
  const float* emb  = (const float*)d_in[1];
  const float* pos  = (const float*)d_in[2];
  const float* ln_g = (const float*)d_in[3];
  const float* ln_b = (const float*)d_in[4];
  const float* inw  = (const float*)d_in[5];
  const float* cw   = (const float*)d_in[6];
  const float* cb   = (const float*)d_in[7];
  const float* xw   = (const float*)d_in[8];
  const float* dtw  = (const float*)d_in[9];
  const float* dtb  = (const float*)d_in[10];
  const float* Alog = (const float*)d_in[11];
  const float* Dp   = (const float*)d_in[12];
  const float* ow   = (const float*)d_in[13];
  const float* flng = (const float*)d_in[14];
  const float* flnb = (const float*)d_in[15];
  const float* pw   = (const float*)d_in[16];
  const float* pb   = (const float*)d_in[17];
  float* out = (float*)d_out;

  // fp32 region
  float* ws    = (float*)d_ws;
  float* x      = ws;                        // M*D
  float* xln    = x + (size_t)M * D;         // M*D (Aprod/Sloc overlay during scan)
  float* xz     = xln + (size_t)M * D;       // M*2DI
  float* xconv  = xz + (size_t)M * 2 * DI;   // M*DI
  float* dbc    = xconv + (size_t)M * DI;    // M*G
  float* dtb_   = dbc + (size_t)M * G;       // M*DI
  float* pooled = dtb_ + (size_t)M * DI;     // B*D
  float* Hstart = pooled + (size_t)B * D;    // B*NCH*DI*DS = 393216
  float* Aprod  = xln;                       // overlay (xln dead during scan)
  float* Sloc   = xln + (size_t)B * NCH * DI * DS;
  // bf16 region
  ushort_t* bfbase   = (ushort_t*)(Hstart + (size_t)B * NCH * DI * DS);
  ushort_t* xln_bf   = bfbase;                                   // M*D
  ushort_t* xconv_bf = xln_bf + (size_t)M * D;                   // M*DI
  ushort_t* ybuf_bf  = xconv_bf + (size_t)M * DI;                // M*DI
  ushort_t* inw_bf   = ybuf_bf + (size_t)M * DI;                 // NL*2DI*D
  ushort_t* xw_bf    = inw_bf + (size_t)NL * 2 * DI * D;         // NL*G*DI
  ushort_t* ow_bf    = xw_bf + (size_t)NL * G * DI;              // NL*D*DI

  // weight pre-conversion (once per call)
  {
    int n8;
    n8 = NL * 2 * DI * D / 8;
    f2bf_kernel<<<(n8 + 255) / 256, 256, 0, stream>>>(inw, inw_bf, n8);
    n8 = NL * G * DI / 8;
    f2bf_kernel<<<(n8 + 255) / 256, 256, 0, stream>>>(xw, xw_bf, n8);
    n8 = NL * D * DI / 8;
    f2bf_kernel<<<(n8 + 255) / 256, 256, 0, stream>>>(ow, ow_bf, n8);
  }

  embed_kernel<<<(M * D + 255) / 256, 256, 0, stream>>>(ids, emb, pos, x);

  for (int i = 0; i < NL; i++) {
    layernorm_kernel<<<M, 64, 0, stream>>>(x, ln_g + i * D, ln_b + i * D, xln, xln_bf);

    dim3 g1(M / 32, (2 * DI) / 64);     // 64 x 24 = 1536 blocks
    gemm_bt_kernel<0><<<g1, 128, 0, stream>>>(xln_bf, inw_bf + (size_t)i * 2 * DI * D, xz, M, 2 * DI, D);

    conv_silu_kernel<<<(M * DI + 255) / 256, 256, 0, stream>>>(
        xz, cw + (size_t)i * DI * DC, cb + (size_t)i * DI, xconv, xconv_bf);

    dim3 g2(M / 32, (G + 63) / 64);     // 64 x 1 (N=56, padded)
    gemm_bt_kernel<0><<<g2, 128, 0, stream>>>(xconv_bf, xw_bf + (size_t)i * G * DI, dbc, M, G, DI);

    dt_kernel<<<M, 256, 0, stream>>>(dbc, dtw + (size_t)i * DI * DTR, dtb + (size_t)i * DI, dtb_);

    dim3 gs(B * NCH, DI / 256);
    scan_pass1<<<gs, 256, 0, stream>>>(dbc, dtb_, xconv,
        Alog + (size_t)i * DI * DS, Aprod, Sloc);
    scan_pass2<<<(B * DI * DS) / 256, 256, 0, stream>>>(Aprod, Sloc, Hstart);
    scan_pass3<<<gs, 256, 0, stream>>>(dbc, dtb_, xconv, xz,
        Alog + (size_t)i * DI * DS, Dp + (size_t)i * DI, Hstart, ybuf_bf);

    dim3 g3(M / 32, D / 64);            // 64 x 6 = 384 blocks
    gemm_bt_kernel<1><<<g3, 128, 0, stream>>>(ybuf_bf, ow_bf + (size_t)i * D * DI, x, M, D, DI);
  }

  layernorm_kernel<<<M, 64, 0, stream>>>(x, flng, flnb, xln, xln_bf);
  pool_kernel<<<B, 128, 0, stream>>>(xln, ids, pooled);
  proj_norm_kernel<<<B, ED, 0, stream>>>(pooled, pw, pb, out);
}

// Round 12
// 1051.779 us; speedup vs baseline: 4.7953x; 1.3257x over previous
//
#include <hip/hip_runtime.h>
#include <hip/hip_bf16.h>
#include <math.h>

#define B 4
#define L 512
#define D 384
#define NL 8
#define DS 16
#define DC 4
#define DI 768
#define DTR 24
#define G (DTR + 2*DS)   // 56
#define ED 256
#define M (B*L)          // 2048
#define NCH 32           // chunks along L
#define CHL (L/NCH)      // 16 tokens per chunk

typedef __attribute__((ext_vector_type(8))) short short8;
typedef __attribute__((ext_vector_type(4))) float f32x4;
typedef unsigned short ushort_t;

// pack two floats -> two bf16 (RNE) in one uint
__device__ inline unsigned bf2(float a, float b) {
  unsigned ua = __float_as_uint(a), ub = __float_as_uint(b);
  ua = (ua + 0x7FFFu + ((ua >> 16) & 1u)) >> 16;
  ub = (ub + 0x7FFFu + ((ub >> 16) & 1u)) >> 16;
  return (ua & 0xFFFFu) | (ub << 16);
}
__device__ inline ushort_t bf1(float a) {
  unsigned u = __float_as_uint(a);
  u = (u + 0x7FFFu + ((u >> 16) & 1u)) >> 16;
  return (ushort_t)u;
}

// ---------------- fp32 -> bf16 bulk convert (n8 = n/8) ----------------
__global__ __launch_bounds__(256) void f2bf_kernel(const float* __restrict__ in,
    ushort_t* __restrict__ out, int n8) {
  int i = blockIdx.x * 256 + threadIdx.x;
  if (i >= n8) return;
  float4 a = *(const float4*)(in + (size_t)i * 8);
  float4 b = *(const float4*)(in + (size_t)i * 8 + 4);
  *(uint4*)(out + (size_t)i * 8) =
      make_uint4(bf2(a.x, a.y), bf2(a.z, a.w), bf2(b.x, b.y), bf2(b.z, b.w));
}

// ---------------- embed: x = emb[ids] + pos ----------------
__global__ __launch_bounds__(256) void embed_kernel(const int* __restrict__ ids,
    const float* __restrict__ emb, const float* __restrict__ pos, float* __restrict__ x) {
  int idx = blockIdx.x * 256 + threadIdx.x;
  if (idx >= M * D) return;
  int m = idx / D, d = idx - m * D;
  int l = m & (L - 1);
  x[idx] = emb[(size_t)ids[m] * D + d] + pos[l * D + d];
}

// ---------------- layernorm: one wave per row; writes fp32 + bf16 ----------
__global__ __launch_bounds__(64) void layernorm_kernel(const float* __restrict__ x,
    const float* __restrict__ g, const float* __restrict__ b,
    float* __restrict__ o, ushort_t* __restrict__ obf) {
  int row = blockIdx.x;
  int t = threadIdx.x;
  const float* xr = x + (size_t)row * D;
  float v[6];
  float s = 0.f;
#pragma unroll
  for (int i = 0; i < 6; i++) { v[i] = xr[t + i * 64]; s += v[i]; }
#pragma unroll
  for (int o_ = 32; o_ > 0; o_ >>= 1) s += __shfl_xor(s, o_);
  float mean = s * (1.0f / D);
  float vs = 0.f;
#pragma unroll
  for (int i = 0; i < 6; i++) { float dd = v[i] - mean; vs += dd * dd; }
#pragma unroll
  for (int o_ = 32; o_ > 0; o_ >>= 1) vs += __shfl_xor(vs, o_);
  float inv = 1.0f / sqrtf(vs * (1.0f / D) + 1e-5f);
  float* orow = o + (size_t)row * D;
  ushort_t* brow = obf + (size_t)row * D;
#pragma unroll
  for (int i = 0; i < 6; i++) {
    int d = t + i * 64;
    float val = (v[i] - mean) * inv * g[d] + b[d];
    orow[d] = val;
    brow[d] = bf1(val);
  }
}

// ---------------- bf16 MFMA GEMM: C[M,N] = A[M,K] @ W[N,K]^T (+C if ADD) ----
// A, W already bf16. Tile 32(M) x 64(N), BK=64, 128 threads = 2 waves.
// Wave w owns N-half w*32. LDS 16B slots XOR-swizzled (slot ^ row&7): 0 conflicts
// (measured R7). Requires Mm%32==0, Kk%64==0; Nn arbitrary (zero-pad + guard).
template <int ADD>
__global__ __launch_bounds__(128) void gemm_bt_kernel(const ushort_t* __restrict__ A,
    const ushort_t* __restrict__ W, float* __restrict__ C, int Mm, int Nn, int Kk) {
  __shared__ uint4 As[32 * 8];   // 4 KB
  __shared__ uint4 Bs[64 * 8];   // 8 KB
  int t = threadIdx.x;
  int lane = t & 63, w = t >> 6;
  int m0 = blockIdx.x * 32, n0 = blockIdx.y * 64;

  f32x4 acc[2][2] = {};

  // staging map: thread t covers A slots {t, t+128}, B slots {t, t+128, t+256, t+384}
  for (int k0 = 0; k0 < Kk; k0 += 64) {
    uint4 av[2], bv[4];
#pragma unroll
    for (int u = 0; u < 2; u++) {
      int q = t + u * 128;
      int row = q >> 3, p = q & 7;
      av[u] = *(const uint4*)(A + (size_t)(m0 + row) * Kk + k0 + ((p ^ (row & 7)) << 3));
    }
#pragma unroll
    for (int u = 0; u < 4; u++) {
      int q = t + u * 128;
      int row = q >> 3, p = q & 7;
      int grow = n0 + row;
      if (grow < Nn)
        bv[u] = *(const uint4*)(W + (size_t)grow * Kk + k0 + ((p ^ (row & 7)) << 3));
      else
        bv[u] = make_uint4(0u, 0u, 0u, 0u);
    }
    __syncthreads();   // previous iteration's LDS reads done
#pragma unroll
    for (int u = 0; u < 2; u++) As[t + u * 128] = av[u];
#pragma unroll
    for (int u = 0; u < 4; u++) Bs[t + u * 128] = bv[u];
    __syncthreads();
#pragma unroll
    for (int kk = 0; kk < 2; kk++) {
      int ks = kk * 4 + (lane >> 4);
      short8 af[2], bfv[2];
#pragma unroll
      for (int i = 0; i < 2; i++) {
        int ra = i * 16 + (lane & 15);
        af[i] = *(short8*)&As[ra * 8 + (ks ^ (ra & 7))];
      }
#pragma unroll
      for (int j = 0; j < 2; j++) {
        int rb = w * 32 + j * 16 + (lane & 15);
        bfv[j] = *(short8*)&Bs[rb * 8 + (ks ^ (rb & 7))];
      }
#pragma unroll
      for (int i = 0; i < 2; i++)
#pragma unroll
        for (int j = 0; j < 2; j++)
          acc[i][j] = __builtin_amdgcn_mfma_f32_16x16x32_bf16(af[i], bfv[j], acc[i][j], 0, 0, 0);
    }
  }

  // C/D layout: col = lane&15, row = (lane>>4)*4 + reg
#pragma unroll
  for (int i = 0; i < 2; i++) {
    int cm = m0 + i * 16 + (lane >> 4) * 4;
#pragma unroll
    for (int j = 0; j < 2; j++) {
      int cn = n0 + w * 32 + j * 16 + (lane & 15);
      if (cn >= Nn) continue;
#pragma unroll
      for (int r = 0; r < 4; r++) {
        size_t off = (size_t)(cm + r) * Nn + cn;
        float v = acc[i][j][r];
        if (ADD) v += C[off];
        C[off] = v;
      }
    }
  }
}

// ---------------- causal conv (DC=4) + silu; writes fp32 + bf16 ----------
__global__ __launch_bounds__(256) void conv_silu_kernel(const float* __restrict__ xz,
    const float* __restrict__ cw, const float* __restrict__ cb,
    float* __restrict__ xc, ushort_t* __restrict__ xcbf) {
  int idx = blockIdx.x * 256 + threadIdx.x;
  if (idx >= M * DI) return;
  int m = idx / DI, e = idx - m * DI;
  int l = m & (L - 1);
  float acc = cb[e];
#pragma unroll
  for (int k = 0; k < DC; k++) {
    int ll = l - (DC - 1) + k;
    if (ll >= 0) acc += xz[(size_t)(m - (DC - 1) + k) * (2 * DI) + e] * cw[e * DC + k];
  }
  float sv = acc / (1.f + __expf(-acc));  // silu
  xc[idx] = sv;
  xcbf[idx] = bf1(sv);
}

// ---------------- dt = softplus(dt_r @ dtw^T + dtb), K=24 ----------------
__global__ __launch_bounds__(256) void dt_kernel(const float* __restrict__ dbc,
    const float* __restrict__ dtw, const float* __restrict__ dtb, float* __restrict__ dt) {
  int tok = blockIdx.x;
  __shared__ float rr[DTR];
  int t = threadIdx.x;
  if (t < DTR) rr[t] = dbc[(size_t)tok * G + t];
  __syncthreads();
  for (int d = t; d < DI; d += 256) {
    float acc = dtb[d];
#pragma unroll
    for (int k = 0; k < DTR; k++) acc += rr[k] * dtw[d * DTR + k];
    dt[(size_t)tok * DI + d] = (acc > 20.f) ? acc : log1pf(expf(acc));
  }
}

// ---------------- chunked selective scan (NCH=32, 64-thread blocks) --------
// grid (B*NCH, DI/64). One thread per (chunk, d); 16 states in registers.
__global__ __launch_bounds__(64) void scan_pass1(const float* __restrict__ dbc,
    const float* __restrict__ dt, const float* __restrict__ xconv,
    const float* __restrict__ A_log, float* __restrict__ Aprod, float* __restrict__ Sloc) {
  int bc = blockIdx.x;               // b*NCH + c
  int b = bc >> 5, c = bc & (NCH - 1);
  int d = blockIdx.y * 64 + threadIdx.x;
  float Av[DS], h[DS], ap[DS];
#pragma unroll
  for (int n = 0; n < DS; n++) {
    Av[n] = -__expf(A_log[d * DS + n]);
    h[n] = 0.f; ap[n] = 1.f;
  }
  size_t tok0 = (size_t)b * L + c * CHL;
  for (int l = 0; l < CHL; l++) {
    size_t tok = tok0 + l;
    float dtv = dt[tok * DI + d];
    float xcv = xconv[tok * DI + d];
    const float4* Bp = (const float4*)(dbc + tok * G + DTR);
    float dbx = dtv * xcv;
#pragma unroll
    for (int q = 0; q < 4; q++) {
      float4 B4 = Bp[q];
      float dA;
      dA = __expf(dtv * Av[q*4+0]); ap[q*4+0] *= dA; h[q*4+0] = dA * h[q*4+0] + dbx * B4.x;
      dA = __expf(dtv * Av[q*4+1]); ap[q*4+1] *= dA; h[q*4+1] = dA * h[q*4+1] + dbx * B4.y;
      dA = __expf(dtv * Av[q*4+2]); ap[q*4+2] *= dA; h[q*4+2] = dA * h[q*4+2] + dbx * B4.z;
      dA = __expf(dtv * Av[q*4+3]); ap[q*4+3] *= dA; h[q*4+3] = dA * h[q*4+3] + dbx * B4.w;
    }
  }
  float* Ap = Aprod + ((size_t)bc * DI + d) * DS;
  float* Sp = Sloc  + ((size_t)bc * DI + d) * DS;
#pragma unroll
  for (int q = 0; q < 4; q++) {
    *(float4*)(Ap + q * 4) = make_float4(ap[q*4+0], ap[q*4+1], ap[q*4+2], ap[q*4+3]);
    *(float4*)(Sp + q * 4) = make_float4(h[q*4+0], h[q*4+1], h[q*4+2], h[q*4+3]);
  }
}

// pass2: compose chunks; overwrites Sloc[o] with the chunk's START state.
__global__ __launch_bounds__(256) void scan_pass2(const float* __restrict__ Aprod,
    float* __restrict__ Sloc) {
  int idx = blockIdx.x * 256 + threadIdx.x;   // b*DI*DS + dn
  int b = idx / (DI * DS);
  int dn = idx - b * DI * DS;
  float h = 0.f;
#pragma unroll
  for (int c = 0; c < NCH; c++) {
    size_t o = (size_t)(b * NCH + c) * DI * DS + dn;
    float a = Aprod[o];
    float s = Sloc[o];
    Sloc[o] = h;          // start state for this chunk
    h = a * h + s;
  }
}

// pass3: re-scan each chunk from its start state (now in Sloc); bf16 y out.
__global__ __launch_bounds__(64) void scan_pass3(const float* __restrict__ dbc,
    const float* __restrict__ dt, const float* __restrict__ xconv,
    const float* __restrict__ xz, const float* __restrict__ A_log,
    const float* __restrict__ Dp, const float* __restrict__ Sloc,
    ushort_t* __restrict__ y) {
  int bc = blockIdx.x;
  int b = bc >> 5, c = bc & (NCH - 1);
  int d = blockIdx.y * 64 + threadIdx.x;
  float Av[DS], h[DS];
  const float* Hs = Sloc + ((size_t)bc * DI + d) * DS;
#pragma unroll
  for (int n = 0; n < DS; n++) {
    Av[n] = -__expf(A_log[d * DS + n]);
    h[n] = Hs[n];
  }
  float Dv = Dp[d];
  size_t tok0 = (size_t)b * L + c * CHL;
  for (int l = 0; l < CHL; l++) {
    size_t tok = tok0 + l;
    float dtv = dt[tok * DI + d];
    float xcv = xconv[tok * DI + d];
    float zv = xz[tok * (2 * DI) + DI + d];
    const float4* BC = (const float4*)(dbc + tok * G + DTR);
    float dbx = dtv * xcv;
    float p = 0.f;
#pragma unroll
    for (int q = 0; q < 4; q++) {
      float4 B4 = BC[q];
      float4 C4 = BC[q + 4];
      float dA;
      dA = __expf(dtv * Av[q*4+0]); h[q*4+0] = dA * h[q*4+0] + dbx * B4.x; p += h[q*4+0] * C4.x;
      dA = __expf(dtv * Av[q*4+1]); h[q*4+1] = dA * h[q*4+1] + dbx * B4.y; p += h[q*4+1] * C4.y;
      dA = __expf(dtv * Av[q*4+2]); h[q*4+2] = dA * h[q*4+2] + dbx * B4.z; p += h[q*4+2] * C4.z;
      dA = __expf(dtv * Av[q*4+3]); h[q*4+3] = dA * h[q*4+3] + dbx * B4.w; p += h[q*4+3] * C4.w;
    }
    float yv = (p + Dv * xcv) * (zv / (1.f + __expf(-zv)));
    y[tok * DI + d] = bf1(yv);
  }
}

// ---------------- masked mean pool ----------------
__global__ __launch_bounds__(128) void pool_kernel(const float* __restrict__ xf,
    const int* __restrict__ ids, float* __restrict__ pooled) {
  int b = blockIdx.x;
  int t = threadIdx.x;
  float cnt = 0.f;
  float sums[3] = {};
  for (int l = 0; l < L; l++) {
    int tok = b * L + l;
    float msk = (ids[tok] != 0) ? 1.f : 0.f;
    cnt += msk;
#pragma unroll
    for (int i = 0; i < 3; i++) sums[i] += msk * xf[(size_t)tok * D + t + i * 128];
  }
  float denom = fmaxf(cnt, 1.f);
#pragma unroll
  for (int i = 0; i < 3; i++) pooled[b * D + t + i * 128] = sums[i] / denom;
}

// ---------------- final proj + L2 normalize ----------------
__global__ __launch_bounds__(256) void proj_norm_kernel(const float* __restrict__ pooled,
    const float* __restrict__ pw, const float* __restrict__ pb, float* __restrict__ out) {
  int b = blockIdx.x;
  int t = threadIdx.x;
  __shared__ float pr[D];
  __shared__ float red[256];
  for (int i = t; i < D; i += 256) pr[i] = pooled[b * D + i];
  __syncthreads();
  float acc = pb[t];
  for (int k = 0; k < D; k++) acc += pr[k] * pw[t * D + k];
  red[t] = acc * acc;
  __syncthreads();
  for (int s = 128; s > 0; s >>= 1) {
    if (t < s) red[t] += red[t + s];
    __syncthreads();
  }
  float nrm = sqrtf(red[0]);
  float scale = 1.f / fmaxf(nrm, 1e-12f);
  out[b * ED + t] = acc * scale;
}

extern "C" void kernel_launch(void* const* d_in, const int* in_sizes, int n_in,
                              void* d_out, int out_size, void* d_ws, size_t ws_size,
                              hipStream_t stream) {
  const int*   ids  = (const int*)d_in[0];
  const float* emb  = (const float*)d_in[1];
  const float* pos  = (const float*)d_in[2];
  const float* ln_g = (const float*)d_in[3];
  const float* ln_b = (const float*)d_in[4];
  const float* inw  = (const float*)d_in[5];
  const float* cw   = (const float*)d_in[6];
  const float* cb   = (const float*)d_in[7];
  const float* xw   = (const float*)d_in[8];
  const float* dtw  = (const float*)d_in[9];
  const float* dtb  = (const float*)d_in[10];
  const float* Alog = (const float*)d_in[11];
  const float* Dp   = (const float*)d_in[12];
  const float* ow   = (const float*)d_in[13];
  const float* flng = (const float*)d_in[14];
  const float* flnb = (const float*)d_in[15];
  const float* pw   = (const float*)d_in[16];
  const float* pb   = (const float*)d_in[17];
  float* out = (float*)d_out;

  // fp32 region
  float* ws    = (float*)d_ws;
  float* x      = ws;                        // M*D
  float* xln    = x + (size_t)M * D;         // M*D
  float* xz     = xln + (size_t)M * D;       // M*2DI
  float* xconv  = xz + (size_t)M * 2 * DI;   // M*DI
  float* dbc    = xconv + (size_t)M * DI;    // M*G
  float* dtb_   = dbc + (size_t)M * G;       // M*DI
  float* pooled = dtb_ + (size_t)M * DI;     // B*D
  // bf16 region
  ushort_t* bfbase   = (ushort_t*)(pooled + (size_t)B * D);
  ushort_t* xln_bf   = bfbase;                                   // M*D
  ushort_t* xconv_bf = xln_bf + (size_t)M * D;                   // M*DI
  ushort_t* ybuf_bf  = xconv_bf + (size_t)M * DI;                // M*DI
  ushort_t* inw_bf   = ybuf_bf + (size_t)M * DI;                 // NL*2DI*D
  ushort_t* xw_bf    = inw_bf + (size_t)NL * 2 * DI * D;         // NL*G*DI
  ushort_t* ow_bf    = xw_bf + (size_t)NL * G * DI;              // NL*D*DI
  // scan scratch (fp32), appended after bf16 region (even ushort count -> 4B aligned)
  float* Aprod = (float*)(ow_bf + (size_t)NL * D * DI);          // B*NCH*DI*DS
  float* Sloc  = Aprod + (size_t)B * NCH * DI * DS;              // B*NCH*DI*DS

  // weight pre-conversion (once per call)
  {
    int n8;
    n8 = NL * 2 * DI * D / 8;
    f2bf_kernel<<<(n8 + 255) / 256, 256, 0, stream>>>(inw, inw_bf, n8);
    n8 = NL * G * DI / 8;
    f2bf_kernel<<<(n8 + 255) / 256, 256, 0, stream>>>(xw, xw_bf, n8);
    n8 = NL * D * DI / 8;
    f2bf_kernel<<<(n8 + 255) / 256, 256, 0, stream>>>(ow, ow_bf, n8);
  }

  embed_kernel<<<(M * D + 255) / 256, 256, 0, stream>>>(ids, emb, pos, x);

  for (int i = 0; i < NL; i++) {
    layernorm_kernel<<<M, 64, 0, stream>>>(x, ln_g + i * D, ln_b + i * D, xln, xln_bf);

    dim3 g1(M / 32, (2 * DI) / 64);     // 64 x 24 = 1536 blocks
    gemm_bt_kernel<0><<<g1, 128, 0, stream>>>(xln_bf, inw_bf + (size_t)i * 2 * DI * D, xz, M, 2 * DI, D);

    conv_silu_kernel<<<(M * DI + 255) / 256, 256, 0, stream>>>(
        xz, cw + (size_t)i * DI * DC, cb + (size_t)i * DI, xconv, xconv_bf);

    dim3 g2(M / 32, (G + 63) / 64);     // 64 x 1 (N=56, padded)
    gemm_bt_kernel<0><<<g2, 128, 0, stream>>>(xconv_bf, xw_bf + (size_t)i * G * DI, dbc, M, G, DI);

    dt_kernel<<<M, 256, 0, stream>>>(dbc, dtw + (size_t)i * DI * DTR, dtb + (size_t)i * DI, dtb_);

    dim3 gs(B * NCH, DI / 64);          // 128 x 12 = 1536 blocks, 64 thr
    scan_pass1<<<gs, 64, 0, stream>>>(dbc, dtb_, xconv,
        Alog + (size_t)i * DI * DS, Aprod, Sloc);
    scan_pass2<<<(B * DI * DS) / 256, 256, 0, stream>>>(Aprod, Sloc);
    scan_pass3<<<gs, 64, 0, stream>>>(dbc, dtb_, xconv, xz,
        Alog + (size_t)i * DI * DS, Dp + (size_t)i * DI, Sloc, ybuf_bf);

    dim3 g3(M / 32, D / 64);            // 64 x 6 = 384 blocks
    gemm_bt_kernel<1><<<g3, 128, 0, stream>>>(ybuf_bf, ow_bf + (size_t)i * D * DI, x, M, D, DI);
  }

  layernorm_kernel<<<M, 64, 0, stream>>>(x, flng, flnb, xln, xln_bf);
  pool_kernel<<<B, 128, 0, stream>>>(xln, ids, pooled);
  proj_norm_kernel<<<B, ED, 0, stream>>>(pooled, pw, pb, out);
}

// Round 13
// 1020.933 us; speedup vs baseline: 4.9402x; 1.0302x over previous
//
#include <hip/hip_runtime.h>
#include <hip/hip_bf16.h>
#include <math.h>

#define B 4
#define L 512
#define D 384
#define NL 8
#define DS 16
#define DC 4
#define DI 768
#define DTR 24
#define G (DTR + 2*DS)   // 56
#define ED 256
#define M (B*L)          // 2048
#define NCH 32           // chunks along L
#define CHL (L/NCH)      // 16 tokens per chunk

typedef __attribute__((ext_vector_type(8))) short short8;
typedef __attribute__((ext_vector_type(4))) float f32x4;
typedef unsigned short ushort_t;

// pack two floats -> two bf16 (RNE) in one uint
__device__ inline unsigned bf2(float a, float b) {
  unsigned ua = __float_as_uint(a), ub = __float_as_uint(b);
  ua = (ua + 0x7FFFu + ((ua >> 16) & 1u)) >> 16;
  ub = (ub + 0x7FFFu + ((ub >> 16) & 1u)) >> 16;
  return (ua & 0xFFFFu) | (ub << 16);
}
__device__ inline ushort_t bf1(float a) {
  unsigned u = __float_as_uint(a);
  u = (u + 0x7FFFu + ((u >> 16) & 1u)) >> 16;
  return (ushort_t)u;
}

// ---------------- fp32 -> bf16 bulk convert, 3 arrays in one launch --------
__global__ __launch_bounds__(256) void f2bf3_kernel(
    const float* __restrict__ a, ushort_t* __restrict__ oa, int na8,
    const float* __restrict__ b, ushort_t* __restrict__ ob, int nb8,
    const float* __restrict__ c, ushort_t* __restrict__ oc, int nc8) {
  int i = blockIdx.x * 256 + threadIdx.x;
  const float* in; ushort_t* out; int j;
  if (i < na8) { in = a; out = oa; j = i; }
  else if (i < na8 + nb8) { in = b; out = ob; j = i - na8; }
  else if (i < na8 + nb8 + nc8) { in = c; out = oc; j = i - na8 - nb8; }
  else return;
  float4 p = *(const float4*)(in + (size_t)j * 8);
  float4 q = *(const float4*)(in + (size_t)j * 8 + 4);
  *(uint4*)(out + (size_t)j * 8) =
      make_uint4(bf2(p.x, p.y), bf2(p.z, p.w), bf2(q.x, q.y), bf2(q.z, q.w));
}

// ---------------- embed: x = emb[ids] + pos ----------------
__global__ __launch_bounds__(256) void embed_kernel(const int* __restrict__ ids,
    const float* __restrict__ emb, const float* __restrict__ pos, float* __restrict__ x) {
  int idx = blockIdx.x * 256 + threadIdx.x;
  if (idx >= M * D) return;
  int m = idx / D, d = idx - m * D;
  int l = m & (L - 1);
  x[idx] = emb[(size_t)ids[m] * D + d] + pos[l * D + d];
}

// ---------------- layernorm: one wave per row; writes fp32 + bf16 ----------
__global__ __launch_bounds__(64) void layernorm_kernel(const float* __restrict__ x,
    const float* __restrict__ g, const float* __restrict__ b,
    float* __restrict__ o, ushort_t* __restrict__ obf) {
  int row = blockIdx.x;
  int t = threadIdx.x;
  const float* xr = x + (size_t)row * D;
  float v[6];
  float s = 0.f;
#pragma unroll
  for (int i = 0; i < 6; i++) { v[i] = xr[t + i * 64]; s += v[i]; }
#pragma unroll
  for (int o_ = 32; o_ > 0; o_ >>= 1) s += __shfl_xor(s, o_);
  float mean = s * (1.0f / D);
  float vs = 0.f;
#pragma unroll
  for (int i = 0; i < 6; i++) { float dd = v[i] - mean; vs += dd * dd; }
#pragma unroll
  for (int o_ = 32; o_ > 0; o_ >>= 1) vs += __shfl_xor(vs, o_);
  float inv = 1.0f / sqrtf(vs * (1.0f / D) + 1e-5f);
  float* orow = o + (size_t)row * D;
  ushort_t* brow = obf + (size_t)row * D;
#pragma unroll
  for (int i = 0; i < 6; i++) {
    int d = t + i * 64;
    float val = (v[i] - mean) * inv * g[d] + b[d];
    orow[d] = val;
    brow[d] = bf1(val);
  }
}

// ---------------- bf16 MFMA GEMM: C[M,N] = A[M,K] @ W[N,K]^T (+C if ADD) ----
template <int ADD>
__global__ __launch_bounds__(128) void gemm_bt_kernel(const ushort_t* __restrict__ A,
    const ushort_t* __restrict__ W, float* __restrict__ C, int Mm, int Nn, int Kk) {
  __shared__ uint4 As[32 * 8];   // 4 KB
  __shared__ uint4 Bs[64 * 8];   // 8 KB
  int t = threadIdx.x;
  int lane = t & 63, w = t >> 6;
  int m0 = blockIdx.x * 32, n0 = blockIdx.y * 64;

  f32x4 acc[2][2] = {};

  for (int k0 = 0; k0 < Kk; k0 += 64) {
    uint4 av[2], bv[4];
#pragma unroll
    for (int u = 0; u < 2; u++) {
      int q = t + u * 128;
      int row = q >> 3, p = q & 7;
      av[u] = *(const uint4*)(A + (size_t)(m0 + row) * Kk + k0 + ((p ^ (row & 7)) << 3));
    }
#pragma unroll
    for (int u = 0; u < 4; u++) {
      int q = t + u * 128;
      int row = q >> 3, p = q & 7;
      int grow = n0 + row;
      if (grow < Nn)
        bv[u] = *(const uint4*)(W + (size_t)grow * Kk + k0 + ((p ^ (row & 7)) << 3));
      else
        bv[u] = make_uint4(0u, 0u, 0u, 0u);
    }
    __syncthreads();
#pragma unroll
    for (int u = 0; u < 2; u++) As[t + u * 128] = av[u];
#pragma unroll
    for (int u = 0; u < 4; u++) Bs[t + u * 128] = bv[u];
    __syncthreads();
#pragma unroll
    for (int kk = 0; kk < 2; kk++) {
      int ks = kk * 4 + (lane >> 4);
      short8 af[2], bfv[2];
#pragma unroll
      for (int i = 0; i < 2; i++) {
        int ra = i * 16 + (lane & 15);
        af[i] = *(short8*)&As[ra * 8 + (ks ^ (ra & 7))];
      }
#pragma unroll
      for (int j = 0; j < 2; j++) {
        int rb = w * 32 + j * 16 + (lane & 15);
        bfv[j] = *(short8*)&Bs[rb * 8 + (ks ^ (rb & 7))];
      }
#pragma unroll
      for (int i = 0; i < 2; i++)
#pragma unroll
        for (int j = 0; j < 2; j++)
          acc[i][j] = __builtin_amdgcn_mfma_f32_16x16x32_bf16(af[i], bfv[j], acc[i][j], 0, 0, 0);
    }
  }

  // C/D layout: col = lane&15, row = (lane>>4)*4 + reg
#pragma unroll
  for (int i = 0; i < 2; i++) {
    int cm = m0 + i * 16 + (lane >> 4) * 4;
#pragma unroll
    for (int j = 0; j < 2; j++) {
      int cn = n0 + w * 32 + j * 16 + (lane & 15);
      if (cn >= Nn) continue;
#pragma unroll
      for (int r = 0; r < 4; r++) {
        size_t off = (size_t)(cm + r) * Nn + cn;
        float v = acc[i][j][r];
        if (ADD) v += C[off];
        C[off] = v;
      }
    }
  }
}

// ---------------- causal conv (DC=4) + silu; writes fp32 + bf16 ----------
__global__ __launch_bounds__(256) void conv_silu_kernel(const float* __restrict__ xz,
    const float* __restrict__ cw, const float* __restrict__ cb,
    float* __restrict__ xc, ushort_t* __restrict__ xcbf) {
  int idx = blockIdx.x * 256 + threadIdx.x;
  if (idx >= M * DI) return;
  int m = idx / DI, e = idx - m * DI;
  int l = m & (L - 1);
  float acc = cb[e];
#pragma unroll
  for (int k = 0; k < DC; k++) {
    int ll = l - (DC - 1) + k;
    if (ll >= 0) acc += xz[(size_t)(m - (DC - 1) + k) * (2 * DI) + e] * cw[e * DC + k];
  }
  float sv = acc / (1.f + __expf(-acc));  // silu
  xc[idx] = sv;
  xcbf[idx] = bf1(sv);
}

// ---------------- chunked selective scan with inline dt ------------------
// dt = softplus(dbc[tok][0:24] . dtw[d] + dtb[d]) computed in-register.
__global__ __launch_bounds__(64) void scan_pass1(const float* __restrict__ dbc,
    const float* __restrict__ xconv, const float* __restrict__ A_log,
    const float* __restrict__ dtw, const float* __restrict__ dtb,
    float* __restrict__ Aprod, float* __restrict__ Sloc) {
  int bc = blockIdx.x;               // b*NCH + c
  int b = bc >> 5, c = bc & (NCH - 1);
  int d = blockIdx.y * 64 + threadIdx.x;
  float Wd[DTR];
#pragma unroll
  for (int q = 0; q < 6; q++)
    *(float4*)&Wd[q * 4] = *(const float4*)(dtw + (size_t)d * DTR + q * 4);
  float dtbv = dtb[d];
  float Av[DS], h[DS], ap[DS];
#pragma unroll
  for (int n = 0; n < DS; n++) {
    Av[n] = -__expf(A_log[d * DS + n]);
    h[n] = 0.f; ap[n] = 1.f;
  }
  size_t tok0 = (size_t)b * L + c * CHL;
  for (int l = 0; l < CHL; l++) {
    size_t tok = tok0 + l;
    const float* row = dbc + tok * G;
    float r_[DTR];
#pragma unroll
    for (int q = 0; q < 6; q++) *(float4*)&r_[q * 4] = *(const float4*)(row + q * 4);
    float sp = dtbv;
#pragma unroll
    for (int k = 0; k < DTR; k++) sp += r_[k] * Wd[k];
    float dtv = (sp > 20.f) ? sp : log1pf(__expf(sp));
    float xcv = xconv[tok * DI + d];
    const float4* Bp = (const float4*)(row + DTR);
    float dbx = dtv * xcv;
#pragma unroll
    for (int q = 0; q < 4; q++) {
      float4 B4 = Bp[q];
      float dA;
      dA = __expf(dtv * Av[q*4+0]); ap[q*4+0] *= dA; h[q*4+0] = dA * h[q*4+0] + dbx * B4.x;
      dA = __expf(dtv * Av[q*4+1]); ap[q*4+1] *= dA; h[q*4+1] = dA * h[q*4+1] + dbx * B4.y;
      dA = __expf(dtv * Av[q*4+2]); ap[q*4+2] *= dA; h[q*4+2] = dA * h[q*4+2] + dbx * B4.z;
      dA = __expf(dtv * Av[q*4+3]); ap[q*4+3] *= dA; h[q*4+3] = dA * h[q*4+3] + dbx * B4.w;
    }
  }
  float* Ap = Aprod + ((size_t)bc * DI + d) * DS;
  float* Sp = Sloc  + ((size_t)bc * DI + d) * DS;
#pragma unroll
  for (int q = 0; q < 4; q++) {
    *(float4*)(Ap + q * 4) = make_float4(ap[q*4+0], ap[q*4+1], ap[q*4+2], ap[q*4+3]);
    *(float4*)(Sp + q * 4) = make_float4(h[q*4+0], h[q*4+1], h[q*4+2], h[q*4+3]);
  }
}

// pass2: compose chunks; overwrites Sloc[o] with the chunk's START state.
__global__ __launch_bounds__(256) void scan_pass2(const float* __restrict__ Aprod,
    float* __restrict__ Sloc) {
  int idx = blockIdx.x * 256 + threadIdx.x;   // b*DI*DS + dn
  int b = idx / (DI * DS);
  int dn = idx - b * DI * DS;
  float h = 0.f;
#pragma unroll
  for (int c = 0; c < NCH; c++) {
    size_t o = (size_t)(b * NCH + c) * DI * DS + dn;
    float a = Aprod[o];
    float s = Sloc[o];
    Sloc[o] = h;          // start state for this chunk
    h = a * h + s;
  }
}

// pass3: re-scan each chunk from its start state (in Sloc); inline dt; bf16 y.
__global__ __launch_bounds__(64) void scan_pass3(const float* __restrict__ dbc,
    const float* __restrict__ xconv, const float* __restrict__ xz,
    const float* __restrict__ A_log, const float* __restrict__ dtw,
    const float* __restrict__ dtb, const float* __restrict__ Dp,
    const float* __restrict__ Sloc, ushort_t* __restrict__ y) {
  int bc = blockIdx.x;
  int b = bc >> 5, c = bc & (NCH - 1);
  int d = blockIdx.y * 64 + threadIdx.x;
  float Wd[DTR];
#pragma unroll
  for (int q = 0; q < 6; q++)
    *(float4*)&Wd[q * 4] = *(const float4*)(dtw + (size_t)d * DTR + q * 4);
  float dtbv = dtb[d];
  float Av[DS], h[DS];
  const float* Hs = Sloc + ((size_t)bc * DI + d) * DS;
#pragma unroll
  for (int n = 0; n < DS; n++) {
    Av[n] = -__expf(A_log[d * DS + n]);
    h[n] = Hs[n];
  }
  float Dv = Dp[d];
  size_t tok0 = (size_t)b * L + c * CHL;
  for (int l = 0; l < CHL; l++) {
    size_t tok = tok0 + l;
    const float* row = dbc + tok * G;
    float r_[DTR];
#pragma unroll
    for (int q = 0; q < 6; q++) *(float4*)&r_[q * 4] = *(const float4*)(row + q * 4);
    float sp = dtbv;
#pragma unroll
    for (int k = 0; k < DTR; k++) sp += r_[k] * Wd[k];
    float dtv = (sp > 20.f) ? sp : log1pf(__expf(sp));
    float xcv = xconv[tok * DI + d];
    float zv = xz[tok * (2 * DI) + DI + d];
    const float4* BC = (const float4*)(row + DTR);
    float dbx = dtv * xcv;
    float p = 0.f;
#pragma unroll
    for (int q = 0; q < 4; q++) {
      float4 B4 = BC[q];
      float4 C4 = BC[q + 4];
      float dA;
      dA = __expf(dtv * Av[q*4+0]); h[q*4+0] = dA * h[q*4+0] + dbx * B4.x; p += h[q*4+0] * C4.x;
      dA = __expf(dtv * Av[q*4+1]); h[q*4+1] = dA * h[q*4+1] + dbx * B4.y; p += h[q*4+1] * C4.y;
      dA = __expf(dtv * Av[q*4+2]); h[q*4+2] = dA * h[q*4+2] + dbx * B4.z; p += h[q*4+2] * C4.z;
      dA = __expf(dtv * Av[q*4+3]); h[q*4+3] = dA * h[q*4+3] + dbx * B4.w; p += h[q*4+3] * C4.w;
    }
    float yv = (p + Dv * xcv) * (zv / (1.f + __expf(-zv)));
    y[tok * DI + d] = bf1(yv);
  }
}

// ---------------- masked mean pool: 2-stage ----------------
__global__ __launch_bounds__(128) void pool_partial(const float* __restrict__ xf,
    const int* __restrict__ ids, float* __restrict__ psum, float* __restrict__ pcnt) {
  int b = blockIdx.x, g = blockIdx.y;
  int t = threadIdx.x;
  float cnt = 0.f;
  float sums[3] = {};
  for (int l = g * 32; l < g * 32 + 32; l++) {
    int tok = b * L + l;
    float msk = (ids[tok] != 0) ? 1.f : 0.f;
    cnt += msk;
#pragma unroll
    for (int i = 0; i < 3; i++) sums[i] += msk * xf[(size_t)tok * D + t + i * 128];
  }
#pragma unroll
  for (int i = 0; i < 3; i++) psum[(size_t)(b * 16 + g) * D + t + i * 128] = sums[i];
  if (t == 0) pcnt[b * 16 + g] = cnt;
}

__global__ __launch_bounds__(128) void pool_final(const float* __restrict__ psum,
    const float* __restrict__ pcnt, float* __restrict__ pooled) {
  int b = blockIdx.x;
  int t = threadIdx.x;
  float cnt = 0.f;
  float s[3] = {};
  for (int g = 0; g < 16; g++) {
    cnt += pcnt[b * 16 + g];
#pragma unroll
    for (int i = 0; i < 3; i++) s[i] += psum[(size_t)(b * 16 + g) * D + t + i * 128];
  }
  float denom = fmaxf(cnt, 1.f);
#pragma unroll
  for (int i = 0; i < 3; i++) pooled[b * D + t + i * 128] = s[i] / denom;
}

// ---------------- final proj + L2 normalize ----------------
__global__ __launch_bounds__(256) void proj_norm_kernel(const float* __restrict__ pooled,
    const float* __restrict__ pw, const float* __restrict__ pb, float* __restrict__ out) {
  int b = blockIdx.x;
  int t = threadIdx.x;
  __shared__ float pr[D];
  __shared__ float red[256];
  for (int i = t; i < D; i += 256) pr[i] = pooled[b * D + i];
  __syncthreads();
  float acc = pb[t];
  for (int k = 0; k < D; k++) acc += pr[k] * pw[t * D + k];
  red[t] = acc * acc;
  __syncthreads();
  for (int s = 128; s > 0; s >>= 1) {
    if (t < s) red[t] += red[t + s];
    __syncthreads();
  }
  float nrm = sqrtf(red[0]);
  float scale = 1.f / fmaxf(nrm, 1e-12f);
  out[b * ED + t] = acc * scale;
}

extern "C" void kernel_launch(void* const* d_in, const int* in_sizes, int n_in,
                              void* d_out, int out_size, void* d_ws, size_t ws_size,
                              hipStream_t stream) {
  const int*   ids  = (const int*)d_in[0];
  const float* emb  = (const float*)d_in[1];
  const float* pos  = (const float*)d_in[2];
  const float* ln_g = (const float*)d_in[3];
  const float* ln_b = (const float*)d_in[4];
  const float* inw  = (const float*)d_in[5];
  const float* cw   = (const float*)d_in[6];
  const float* cb   = (const float*)d_in[7];
  const float* xw   = (const float*)d_in[8];
  const float* dtw  = (const float*)d_in[9];
  const float* dtb  = (const float*)d_in[10];
  const float* Alog = (const float*)d_in[11];
  const float* Dp   = (const float*)d_in[12];
  const float* ow   = (const float*)d_in[13];
  const float* flng = (const float*)d_in[14];
  const float* flnb = (const float*)d_in[15];
  const float* pw   = (const float*)d_in[16];
  const float* pb   = (const float*)d_in[17];
  float* out = (float*)d_out;

  // fp32 region
  float* ws    = (float*)d_ws;
  float* x      = ws;                        // M*D
  float* xln    = x + (size_t)M * D;         // M*D
  float* xz     = xln + (size_t)M * D;       // M*2DI
  float* xconv  = xz + (size_t)M * 2 * DI;   // M*DI
  float* dbc    = xconv + (size_t)M * DI;    // M*G
  float* pooled = dbc + (size_t)M * G;       // B*D
  // bf16 region
  ushort_t* bfbase   = (ushort_t*)(pooled + (size_t)B * D);
  ushort_t* xln_bf   = bfbase;                                   // M*D
  ushort_t* xconv_bf = xln_bf + (size_t)M * D;                   // M*DI
  ushort_t* ybuf_bf  = xconv_bf + (size_t)M * DI;                // M*DI
  ushort_t* inw_bf   = ybuf_bf + (size_t)M * DI;                 // NL*2DI*D
  ushort_t* xw_bf    = inw_bf + (size_t)NL * 2 * DI * D;         // NL*G*DI
  ushort_t* ow_bf    = xw_bf + (size_t)NL * G * DI;              // NL*D*DI
  // fp32 scan + pool scratch after bf16 region (even ushort count -> aligned)
  float* Aprod = (float*)(ow_bf + (size_t)NL * D * DI);          // B*NCH*DI*DS
  float* Sloc  = Aprod + (size_t)B * NCH * DI * DS;              // B*NCH*DI*DS
  float* psum  = Sloc + (size_t)B * NCH * DI * DS;               // B*16*D
  float* pcnt  = psum + (size_t)B * 16 * D;                      // B*16

  // weight pre-conversion, one launch
  {
    int na8 = NL * 2 * DI * D / 8;
    int nb8 = NL * G * DI / 8;
    int nc8 = NL * D * DI / 8;
    int tot = na8 + nb8 + nc8;
    f2bf3_kernel<<<(tot + 255) / 256, 256, 0, stream>>>(
        inw, inw_bf, na8, xw, xw_bf, nb8, ow, ow_bf, nc8);
  }

  embed_kernel<<<(M * D + 255) / 256, 256, 0, stream>>>(ids, emb, pos, x);

  for (int i = 0; i < NL; i++) {
    layernorm_kernel<<<M, 64, 0, stream>>>(x, ln_g + i * D, ln_b + i * D, xln, xln_bf);

    dim3 g1(M / 32, (2 * DI) / 64);     // 64 x 24 = 1536 blocks
    gemm_bt_kernel<0><<<g1, 128, 0, stream>>>(xln_bf, inw_bf + (size_t)i * 2 * DI * D, xz, M, 2 * DI, D);

    conv_silu_kernel<<<(M * DI + 255) / 256, 256, 0, stream>>>(
        xz, cw + (size_t)i * DI * DC, cb + (size_t)i * DI, xconv, xconv_bf);

    dim3 g2(M / 32, (G + 63) / 64);     // 64 x 1 (N=56, padded)
    gemm_bt_kernel<0><<<g2, 128, 0, stream>>>(xconv_bf, xw_bf + (size_t)i * G * DI, dbc, M, G, DI);

    dim3 gs(B * NCH, DI / 64);          // 128 x 12 = 1536 blocks, 64 thr
    scan_pass1<<<gs, 64, 0, stream>>>(dbc, xconv,
        Alog + (size_t)i * DI * DS, dtw + (size_t)i * DI * DTR, dtb + (size_t)i * DI,
        Aprod, Sloc);
    scan_pass2<<<(B * DI * DS) / 256, 256, 0, stream>>>(Aprod, Sloc);
    scan_pass3<<<gs, 64, 0, stream>>>(dbc, xconv, xz,
        Alog + (size_t)i * DI * DS, dtw + (size_t)i * DI * DTR, dtb + (size_t)i * DI,
        Dp + (size_t)i * DI, Sloc, ybuf_bf);

    dim3 g3(M / 32, D / 64);            // 64 x 6 = 384 blocks
    gemm_bt_kernel<1><<<g3, 128, 0, stream>>>(ybuf_bf, ow_bf + (size_t)i * D * DI, x, M, D, DI);
  }

  layernorm_kernel<<<M, 64, 0, stream>>>(x, flng, flnb, xln, xln_bf);
  dim3 gp(B, 16);
  pool_partial<<<gp, 128, 0, stream>>>(xln, ids, psum, pcnt);
  pool_final<<<B, 128, 0, stream>>>(psum, pcnt, pooled);
  proj_norm_kernel<<<B, ED, 0, stream>>>(pooled, pw, pb, out);
}